// Round 12
// baseline (272.065 us; speedup 1.0000x reference)
//
#include <hip/hip_runtime.h>
#include <hip/hip_bf16.h>
#include <cstdint>
#include <cmath>

#define BTOT 32768L
#define OSIG 0L
#define OEXC (BTOT*40L)
#define OPREV (OEXC + BTOT*256L)
#define OH1 (OPREV + BTOT*256L)
#define OH2 (OH1 + BTOT*160L)
#define OH3 (OH2 + BTOT*128L)
#define ONS4 (OH3 + BTOT*128L)

typedef __attribute__((ext_vector_type(8))) short short8;
typedef __attribute__((ext_vector_type(4))) short short4v;
typedef __attribute__((ext_vector_type(4))) float f32x4;

#define AP 968   // ACT pitch (bf16 elems), %8==0 for 16B alignment

// ACT column map: identical to R10 (see lifetime audit there), 32 rows now.
// ws layout (bf16). All blocks [Npad][KP], row-major, zero-padded.
#define W_F0     0L        // [192][352]
#define W_F0G    67584L    // [192][192]
#define W_PG     104448L   // [16][192]
#define W_IH1R   107520L   // [192][288]
#define W_IH1Z   162816L
#define W_IH1N   218112L
#define W_HH1R   273408L   // [192][192]
#define W_HH1Z   310272L
#define W_HH1N   347136L
#define W_GLU1   384000L   // [192][192]
#define W_IH2R   420864L   // [128][256]
#define W_IH2Z   453632L
#define W_IH2N   486400L
#define W_HH2R   519168L   // [128][128]
#define W_HH2Z   535552L
#define W_HH2N   551936L
#define W_GLU2   568320L   // [128][128]
#define W_IH3R   584704L   // [128][224]
#define W_IH3Z   613376L
#define W_IH3N   642048L
#define W_HH3R   670720L   // [128][128]
#define W_HH3Z   687104L
#define W_HH3N   703488L
#define W_GLU3   719872L   // [128][128]
#define W_SKIP   736256L   // [128][960] column-permuted to ACT map
#define W_SKIPG  859136L   // [128][128]
#define W_SIG    875520L   // [64][128]

__device__ __forceinline__ float sigm(float x){ return 1.0f/(1.0f+__expf(-x)); }
__device__ __forceinline__ float tanh_f(float x){
    float e = __expf(2.0f*x);
    return 1.0f - 2.0f/(e+1.0f);
}
__device__ __forceinline__ uint16_t f2bf(float x){
    __hip_bfloat16 h = __float2bfloat16(x);
    return *(uint16_t*)&h;
}
__device__ __forceinline__ float bf2f(uint16_t h){
    union { float f; uint32_t u; } v; v.u = ((uint32_t)h)<<16;
    return v.f;
}
__device__ __forceinline__ short4v pack4(float4 v){
    short4v r;
    r.x=(short)f2bf(v.x); r.y=(short)f2bf(v.y); r.z=(short)f2bf(v.z); r.w=(short)f2bf(v.w);
    return r;
}

// ---------------- prep: fp32 weights -> padded bf16 blocks in ws ----------------
struct PrepArgs { const float* s[15]; };

__global__ __launch_bounds__(64) void prep_kernel(PrepArgs pa, uint16_t* dst){
    static const long J[27][8] = {
        {0,  0,192,328,352,192, W_F0,   0},
        {1,  0,192,192,192,192, W_F0G,  0},
        {13, 0,  4,192,192, 16, W_PG,   0},
        {2,  0,160,272,288,192, W_IH1R, 0},
        {2,160,160,272,288,192, W_IH1Z, 0},
        {2,320,160,272,288,192, W_IH1N, 0},
        {3,  0,160,160,192,192, W_HH1R, 0},
        {3,160,160,160,192,192, W_HH1Z, 0},
        {3,320,160,160,192,192, W_HH1N, 0},
        {4,  0,160,160,192,192, W_GLU1, 0},
        {5,  0,128,240,256,128, W_IH2R, 0},
        {5,128,128,240,256,128, W_IH2Z, 0},
        {5,256,128,240,256,128, W_IH2N, 0},
        {6,  0,128,128,128,128, W_HH2R, 0},
        {6,128,128,128,128,128, W_HH2Z, 0},
        {6,256,128,128,128,128, W_HH2N, 0},
        {7,  0,128,128,128,128, W_GLU2, 0},
        {8,  0,128,208,224,128, W_IH3R, 0},
        {8,128,128,208,224,128, W_IH3Z, 0},
        {8,256,128,208,224,128, W_IH3N, 0},
        {9,  0,128,128,128,128, W_HH3R, 0},
        {9,128,128,128,128,128, W_HH3Z, 0},
        {9,256,128,128,128,128, W_HH3N, 0},
        {10, 0,128,128,128,128, W_GLU3, 0},
        {11, 0,128,688,960,128, W_SKIP, 1},
        {12, 0,128,128,128,128, W_SKIPG,0},
        {14, 0, 40,128,128, 64, W_SIG,  0},
    };
    long row = blockIdx.x;
    int j = 0;
    while (row >= J[j][5]) { row -= J[j][5]; ++j; }
    const float* src = pa.s[J[j][0]];
    const long ro = J[j][1], N = J[j][2], K = J[j][3], KP = J[j][4];
    const int type = (int)J[j][7];
    uint16_t* d = dst + J[j][6] + row*KP;
    for (long k = threadIdx.x; k < KP; k += 64){
        float v = 0.0f;
        if (row < N){
            if (type == 0){
                if (k < K) v = src[(ro+row)*K + k];
            } else {
                long s = -1;
                if (k < 192) s = 416 + k;                        // fwc0
                else if (k >= 232 && k < 272) s = 648 + (k-232); // prev
                else if (k >= 288 && k < 448) s = (k-288);       // g1
                else if (k >= 544 && k < 672) s = 160 + (k-544); // g2
                else if (k >= 768 && k < 896) s = 288 + (k-768); // g3
                else if (k >= 896 && k < 936) s = 608 + (k-896); // pf4
                if (s >= 0) v = src[row*688 + s];
            }
        }
        d[k] = f2bf(v);
    }
}

// ---------------- dual-m-tile wave GEMM with 6-deep B-load ring prefetch ----------------
template<int KS, int CNT>
__device__ __forceinline__ void wgemm4(f32x4 (&acc)[CNT][2],
    const uint16_t* __restrict__ Bw, int KP,
    const uint16_t* A, int P, int w, int r16, int g)
{
    constexpr int T = KS*CNT;
    constexpr int PF = (T < 6) ? T : 6;
    const uint16_t* ap = A + r16*P + g*8;
    const uint16_t* bbase = Bw + (size_t)(w*16 + r16)*KP + g*8;
    short8 ring[PF];
    #pragma unroll
    for (int t=0;t<PF;++t)
        ring[t] = *(const short8*)(bbase + (size_t)(t%CNT)*128*KP + (size_t)(t/CNT)*32);
    short8 af[2];
    #pragma unroll
    for (int t=0;t<T;++t){
        const int s = t/CNT, i = t%CNT;
        if (i==0){
            #pragma unroll
            for (int mt=0;mt<2;++mt) af[mt] = *(const short8*)(ap + mt*16*P + s*32);
        }
        short8 bf = ring[t%PF];
        if (t+PF < T)
            ring[t%PF] = *(const short8*)(bbase + (size_t)((t+PF)%CNT)*128*KP + (size_t)((t+PF)/CNT)*32);
        #pragma unroll
        for (int mt=0;mt<2;++mt)
            acc[i][mt] = __builtin_amdgcn_mfma_f32_16x16x32_bf16(af[mt], bf, acc[i][mt],0,0,0);
    }
}
template<int CNT> __device__ __forceinline__ void zacc(f32x4 (&a)[CNT][2]){
    f32x4 z4 = {0.f,0.f,0.f,0.f};
    #pragma unroll
    for (int i=0;i<CNT;++i){
        #pragma unroll
        for (int mt=0;mt<2;++mt) a[i][mt]=z4;
    }
}

// ---------------- GRU1 merged h-phase (H=160, x=[0,288) K288, h=[544,736) K192) ----------------
template<int CNT>
__device__ __forceinline__ void gru1_h(const uint16_t* __restrict__ W, uint16_t* ACTp,
    const float* __restrict__ s1g, float* __restrict__ out,
    float (&hk)[2][2][4], int row0, int w, int r16, int g)
{
    f32x4 gx[CNT][2], gh[CNT][2], ra[CNT][2], za[CNT][2];
    zacc(gx); zacc(gh); zacc(ra); zacc(za);
    wgemm4<9,CNT>(gx, W+W_IH1N, 288, ACTp,     AP, w,r16,g);
    wgemm4<9,CNT>(ra, W+W_IH1R, 288, ACTp,     AP, w,r16,g);
    wgemm4<9,CNT>(za, W+W_IH1Z, 288, ACTp,     AP, w,r16,g);
    wgemm4<6,CNT>(gh, W+W_HH1N, 192, ACTp+544, AP, w,r16,g);
    wgemm4<6,CNT>(ra, W+W_HH1R, 192, ACTp+544, AP, w,r16,g);
    wgemm4<6,CNT>(za, W+W_HH1Z, 192, ACTp+544, AP, w,r16,g);
    #pragma unroll
    for (int i=0;i<CNT;++i){
        int n = (w+8*i)*16 + r16;
        #pragma unroll
        for (int mt=0;mt<2;++mt){
            #pragma unroll
            for (int q=0;q<4;++q){
                int mrow = mt*16+g*4+q;
                float h = 0.f;
                if (n < 160){
                    float hpv = s1g[(long)(row0+mrow)*160 + n];
                    float r = sigm(ra[i][mt][q]);
                    float z = sigm(za[i][mt][q]);
                    float nn = tanh_f(gx[i][mt][q] + r*gh[i][mt][q]);
                    h = (1.f-z)*nn + z*hpv;
                    out[OH1 + (long)(row0+mrow)*160 + n] = h;
                }
                hk[i][mt][q] = h;
                ACTp[mrow*AP+768+n] = f2bf(h);   // HB1 (h; zeros n>=160)
            }
        }
    }
}
template<int CNT>
__device__ __forceinline__ void glu1(const uint16_t* __restrict__ W, uint16_t* ACTp,
                                     float (&hk)[2][2][4], int w, int r16, int g){
    f32x4 gl[CNT][2];
    zacc(gl);
    wgemm4<6,CNT>(gl, W+W_GLU1, 192, ACTp+768, AP, w,r16,g);
    #pragma unroll
    for (int i=0;i<CNT;++i){
        int n = (w+8*i)*16 + r16;
        if (n < 160){
            #pragma unroll
            for (int mt=0;mt<2;++mt)
                #pragma unroll
                for (int q=0;q<4;++q){
                    int mrow = mt*16+g*4+q;
                    ACTp[mrow*AP + 288 + n] = f2bf(hk[i][mt][q]*sigm(gl[i][mt][q]));  // g1
                }
        }
    }
}

// ---------------- GRU2/3 merged h-phase (H=128) ----------------
template<int KSX, int KSH>
__device__ __forceinline__ void gru23_h(
    const uint16_t* __restrict__ Wxr, const uint16_t* __restrict__ Wxz, const uint16_t* __restrict__ Wxn, int KPX,
    const uint16_t* __restrict__ Whr, const uint16_t* __restrict__ Whz, const uint16_t* __restrict__ Whn, int KPH,
    const uint16_t* XA, const uint16_t* HA, int HAP,
    const float* __restrict__ sg, float* __restrict__ outp, long obase,
    uint16_t* HBdst, int HBpitch,
    float (&hk)[2][4], int row0, int w, int r16, int g)
{
    const int n = w*16 + r16;
    f32x4 gx[1][2], gh[1][2], ra[1][2], za[1][2];
    zacc(gx); zacc(gh); zacc(ra); zacc(za);
    wgemm4<KSX,1>(gx, Wxn, KPX, XA, AP, w,r16,g);
    wgemm4<KSX,1>(ra, Wxr, KPX, XA, AP, w,r16,g);
    wgemm4<KSX,1>(za, Wxz, KPX, XA, AP, w,r16,g);
    wgemm4<KSH,1>(gh, Whn, KPH, HA, HAP, w,r16,g);
    wgemm4<KSH,1>(ra, Whr, KPH, HA, HAP, w,r16,g);
    wgemm4<KSH,1>(za, Whz, KPH, HA, HAP, w,r16,g);
    #pragma unroll
    for (int mt=0;mt<2;++mt){
        #pragma unroll
        for (int q=0;q<4;++q){
            int mrow = mt*16+g*4+q;
            float hpv = sg[(long)(row0+mrow)*128 + n];
            float r = sigm(ra[0][mt][q]), z = sigm(za[0][mt][q]);
            float nn = tanh_f(gx[0][mt][q] + r*gh[0][mt][q]);
            float h = (1.f-z)*nn + z*hpv;
            outp[obase + (long)(row0+mrow)*128 + n] = h;
            hk[mt][q] = h;
            if (HBdst) HBdst[mrow*HBpitch + n] = f2bf(h);
        }
    }
}

// ---------------- main kernel: 32 rows / block, 512 threads, 2 blocks/CU ----------------
extern "C" __global__ __launch_bounds__(512, 4)
void fargan_mfma(const float* __restrict__ cond, const float* __restrict__ prev_pred,
                 const float* __restrict__ exc_mem, const float* __restrict__ period,
                 const float* __restrict__ s1, const float* __restrict__ s2,
                 const float* __restrict__ s3, const float* __restrict__ s4,
                 const float* __restrict__ w_gain, const float* __restrict__ b_gain,
                 const float* __restrict__ b_pg,
                 const uint16_t* __restrict__ W, float* __restrict__ out)
{
    __shared__ __align__(16) uint16_t ACT[32*AP];
    __shared__ __align__(16) uint16_t SH[32*136];
    __shared__ uint16_t FPITCHb[32*40];
    __shared__ float GAIN[32];
    __shared__ float PGs[32][4];

    const int tid = threadIdx.x;
    const int row0 = blockIdx.x * 32;
    const int w = tid >> 6, l = tid & 63, r16 = l & 15, g = l >> 4;
    const int rr = tid >> 4, c16 = tid & 15;
    const long grow = row0 + rr;

    // ======== stage A (float4-vectorized; 16 threads/row) ========
    const float* exc_row = exc_mem + grow*256;

    float a0 = 0.f;
    {
        const float4* c4 = (const float4*)(cond + grow*80);
        const float4* g4 = (const float4*)w_gain;
        float4* on4 = (float4*)(out + ONS4 + grow*164);
        for (int i=c16;i<20;i+=16){
            float4 cv = c4[i], gv = g4[i];
            a0 += cv.x*gv.x + cv.y*gv.y + cv.z*gv.z + cv.w*gv.w;
            *(short4v*)&ACT[rr*AP + 164 + 4*i] = pack4(cv);
            on4[i] = cv;
        }
    }
    a0 += __shfl_xor(a0,8,16); a0 += __shfl_xor(a0,4,16);
    a0 += __shfl_xor(a0,2,16); a0 += __shfl_xor(a0,1,16);
    float gn = 0.2f + 0.8f*sigm(a0 + b_gain[0]);
    if (!(gn==gn)) gn = 1.0f;
    gn = fminf(fmaxf(gn, 0.001f), 20.0f);
    float inv = 1.0f/(1e-5f+gn);
    if (c16==0) GAIN[rr] = gn;

    float p = period[grow];
    p = (fabsf(p) <= 3.0e38f) ? p : 128.0f;
    p = fminf(fmaxf(p, 32.0f), 255.0f);

    for (int e=c16;e<44;e+=16){
        float idxf = 254.0f - p + (float)e;
        float idx0 = floorf(idxf);
        float al = fminf(fmaxf(idxf-idx0, 0.f), 1.f);
        int i0 = (int)fminf(fmaxf(idx0, 0.f), 255.f);
        int i1 = (int)fminf(fmaxf(idx0+1.f, 0.f), 255.f);
        float pr = (1.f-al)*exc_row[i0] + al*exc_row[i1];
        float pn = pr*inv;
        ACT[rr*AP + 244 + e] = f2bf(pn);             // XCAT pred_n
        out[ONS4 + grow*164 + 80 + e] = pn;
        if (e>=2 && e<42){
            out[OPREV + grow*256 + 216 + (e-2)] = pr;
            FPITCHb[rr*40 + (e-2)] = f2bf(pn);
        }
    }
    {
        const float4* pv4 = (const float4*)(exc_row + 216);
        float4* onp = (float4*)(out + ONS4 + grow*164 + 124);
        for (int i=c16;i<10;i+=16){
            float4 v = pv4[i];
            v.x*=inv; v.y*=inv; v.z*=inv; v.w*=inv;
            *(short4v*)&ACT[rr*AP + 288 + 4*i] = pack4(v);   // XCAT prev (stable until GLU1)
            onp[i] = v;
        }
    }
    {
        const float4* s44 = (const float4*)(s4 + grow*164);
        for (int i=c16;i<41;i+=16)
            *(short4v*)&ACT[rr*AP + 4*i] = pack4(s44[i]);    // XCAT s4
        const float4* s14 = (const float4*)(s1 + grow*160);
        for (int i=c16;i<40;i+=16)
            *(short4v*)&ACT[rr*AP + 544 + 4*i] = pack4(s14[i]);  // s1-state
    }
    for (int i=328+c16;i<352;i+=16) ACT[rr*AP + i] = 0;          // XCAT pad
    for (int i=704+c16;i<736;i+=16) ACT[rr*AP + i] = 0;          // s1 pad
    {
        const float4* pp4 = (const float4*)(prev_pred + grow*256 + 40);
        const float4* ex4 = (const float4*)(exc_row + 40);
        float4* op4 = (float4*)(out + OPREV + grow*256);
        float4* oe4 = (float4*)(out + OEXC + grow*256);
        for (int i=c16;i<54;i+=16){ op4[i] = pp4[i]; oe4[i] = ex4[i]; }
    }
    __syncthreads();

    float fwk[2][2][4];

    // ======== fwc0: tanh(XCAT[0,352) @ W_F0^T) -> FWRAW @ [352,544) ========
    if (w < 4){
        f32x4 av[2][2]; zacc(av);
        wgemm4<11,2>(av, W+W_F0, 352, ACT, AP, w,r16,g);
        #pragma unroll
        for (int i=0;i<2;++i){
            int n = (w+8*i)*16 + r16;
            #pragma unroll
            for (int mt=0;mt<2;++mt)
                #pragma unroll
                for (int q=0;q<4;++q){
                    int mrow = mt*16+g*4+q;
                    float t = tanh_f(av[i][mt][q]);
                    fwk[i][mt][q] = t;
                    ACT[mrow*AP+352+n] = f2bf(t);
                }
        }
    } else {
        f32x4 av[1][2]; zacc(av);
        wgemm4<11,1>(av, W+W_F0, 352, ACT, AP, w,r16,g);
        int n = w*16 + r16;
        #pragma unroll
        for (int mt=0;mt<2;++mt)
            #pragma unroll
            for (int q=0;q<4;++q){
                int mrow = mt*16+g*4+q;
                float t = tanh_f(av[0][mt][q]);
                fwk[0][mt][q] = t;
                ACT[mrow*AP+352+n] = f2bf(t);
            }
    }
    __syncthreads();

    // ======== f0g GLU -> fwc0 @ [0,192) ========
    if (w < 4){
        f32x4 av[2][2]; zacc(av);
        wgemm4<6,2>(av, W+W_F0G, 192, ACT+352, AP, w,r16,g);
        #pragma unroll
        for (int i=0;i<2;++i){
            int n = (w+8*i)*16 + r16;
            #pragma unroll
            for (int mt=0;mt<2;++mt)
                #pragma unroll
                for (int q=0;q<4;++q){
                    int mrow = mt*16+g*4+q;
                    ACT[mrow*AP+n] = f2bf(fwk[i][mt][q]*sigm(av[i][mt][q]));
                }
        }
    } else {
        f32x4 av[1][2]; zacc(av);
        wgemm4<6,1>(av, W+W_F0G, 192, ACT+352, AP, w,r16,g);
        int n = w*16 + r16;
        #pragma unroll
        for (int mt=0;mt<2;++mt)
            #pragma unroll
            for (int q=0;q<4;++q){
                int mrow = mt*16+g*4+q;
                ACT[mrow*AP+n] = f2bf(fwk[0][mt][q]*sigm(av[0][mt][q]));
            }
    }
    __syncthreads();

    // ======== pitch gain (redundant per wave; wave0 writes) ========
    {
        f32x4 av[1][2]; zacc(av);
        wgemm4<6,1>(av, W+W_PG, 192, ACT, AP, 0, r16, g);
        if (w==0 && r16<4){
            float bp = b_pg[r16];
            #pragma unroll
            for (int mt=0;mt<2;++mt)
                #pragma unroll
                for (int q=0;q<4;++q)
                    PGs[mt*16+g*4+q][r16] = sigm(av[0][mt][q] + bp);
        }
    }
    __syncthreads();

    // ======== pf1 @[192,232); prev -> stable [232,272) ========
    for (int i=c16;i<40;i+=16){
        ACT[rr*AP+192+i] = f2bf(PGs[rr][0]*bf2f(FPITCHb[rr*40+i]));
        ACT[rr*AP+232+i] = ACT[rr*AP+288+i];
    }
    __syncthreads();

    // ======== GRU1 merged h-phase ========
    float hk1[2][2][4];
    if (w < 4) gru1_h<2>(W, ACT, s1, out, hk1, row0, w,r16,g);
    else       gru1_h<1>(W, ACT, s1, out, hk1, row0, w,r16,g);
    __syncthreads();

    // ======== GLU1 -> g1 @[288,448); stage s2 -> [544,672), pf2@448, prev2@488, z@528 ========
    if (w < 4) glu1<2>(W, ACT, hk1, w,r16,g); else glu1<1>(W, ACT, hk1, w,r16,g);
    {
        const float4* s24 = (const float4*)(s2 + grow*128);
        for (int i=c16;i<32;i+=16)
            *(short4v*)&ACT[rr*AP + 544 + 4*i] = pack4(s24[i]);
    }
    for (int i=c16;i<40;i+=16){
        ACT[rr*AP+448+i] = f2bf(PGs[rr][1]*bf2f(FPITCHb[rr*40+i]));
        ACT[rr*AP+488+i] = ACT[rr*AP+232+i];
    }
    for (int i=528+c16;i<544;i+=16) ACT[rr*AP+i] = 0;
    __syncthreads();

    // ======== GRU2: x=[288,544) K256, h=[544,672); HB2 -> [768,896) ========
    float hk[2][4];
    gru23_h<8,4>(W+W_IH2R, W+W_IH2Z, W+W_IH2N, 256,
                 W+W_HH2R, W+W_HH2Z, W+W_HH2N, 128,
                 ACT+288, ACT+544, AP, s2, out, OH2,
                 ACT+768, AP, hk, row0, w,r16,g);
    __syncthreads();

    // ======== GLU2 -> g2 @[544,672); stage s3 -> SH, pf3@672, prev3@712, z@752 ========
    {
        f32x4 gl[1][2]; zacc(gl);
        wgemm4<4,1>(gl, W+W_GLU2, 128, ACT+768, AP, w,r16,g);
        int n = w*16 + r16;
        #pragma unroll
        for (int mt=0;mt<2;++mt)
            #pragma unroll
            for (int q=0;q<4;++q){
                int mrow = mt*16+g*4+q;
                ACT[mrow*AP+544+n] = f2bf(hk[mt][q]*sigm(gl[0][mt][q]));
            }
    }
    {
        const float4* s34 = (const float4*)(s3 + grow*128);
        for (int i=c16;i<32;i+=16)
            *(short4v*)&SH[rr*136 + 4*i] = pack4(s34[i]);
    }
    for (int i=c16;i<40;i+=16){
        ACT[rr*AP+672+i] = f2bf(PGs[rr][2]*bf2f(FPITCHb[rr*40+i]));
        ACT[rr*AP+712+i] = ACT[rr*AP+232+i];
    }
    for (int i=752+c16;i<768;i+=16) ACT[rr*AP+i] = 0;
    __syncthreads();

    // ======== GRU3: x=[544,768) K224, h=SH (pitch 136); hk kept in regs ========
    gru23_h<7,4>(W+W_IH3R, W+W_IH3Z, W+W_IH3N, 224,
                 W+W_HH3R, W+W_HH3Z, W+W_HH3N, 128,
                 ACT+544, SH, 136, s3, out, OH3,
                 (uint16_t*)nullptr, 0, hk, row0, w,r16,g);
    __syncthreads();

    // ======== HB3 -> SH (s3 dead) ========
    {
        int n = w*16 + r16;
        #pragma unroll
        for (int mt=0;mt<2;++mt)
            #pragma unroll
            for (int q=0;q<4;++q)
                SH[(mt*16+g*4+q)*136 + n] = f2bf(hk[mt][q]);
    }
    __syncthreads();

    // ======== GLU3 (reads SH, pitch 136) -> g3 @[768,896); pf4@896 ========
    {
        f32x4 gl[1][2]; zacc(gl);
        {
            const uint16_t* ap = SH + r16*136 + g*8;
            const uint16_t* bbase = W + W_GLU3 + (size_t)(w*16 + r16)*128 + g*8;
            short8 ring[4];
            #pragma unroll
            for (int t=0;t<4;++t) ring[t] = *(const short8*)(bbase + t*32);
            #pragma unroll
            for (int s=0;s<4;++s){
                short8 af[2];
                #pragma unroll
                for (int mt=0;mt<2;++mt) af[mt] = *(const short8*)(ap + mt*16*136 + s*32);
                short8 bf = ring[s];
                #pragma unroll
                for (int mt=0;mt<2;++mt)
                    gl[0][mt] = __builtin_amdgcn_mfma_f32_16x16x32_bf16(af[mt], bf, gl[0][mt],0,0,0);
            }
        }
        int n = w*16 + r16;
        #pragma unroll
        for (int mt=0;mt<2;++mt)
            #pragma unroll
            for (int q=0;q<4;++q){
                int mrow = mt*16+g*4+q;
                ACT[mrow*AP+768+n] = f2bf(hk[mt][q]*sigm(gl[0][mt][q]));
            }
    }
    for (int i=c16;i<40;i+=16)
        ACT[rr*AP+896+i] = f2bf(PGs[rr][3]*bf2f(FPITCHb[rr*40+i]));
    __syncthreads();

    // ======== skip: tanh(ACT[0,960) @ W_SKIP^T) -> SK @ SH ========
    float skk[2][4];
    {
        f32x4 av[1][2]; zacc(av);
        wgemm4<30,1>(av, W+W_SKIP, 960, ACT, AP, w,r16,g);
        int n = w*16 + r16;
        #pragma unroll
        for (int mt=0;mt<2;++mt)
            #pragma unroll
            for (int q=0;q<4;++q){
                int mrow = mt*16+g*4+q;
                float t = tanh_f(av[0][mt][q]);
                skk[mt][q] = t;
                SH[mrow*136+n] = f2bf(t);
            }
    }
    __syncthreads();
    // ======== skip GLU (reads SH, pitch 136) -> SK2 @ ACT[0,128) ========
    {
        f32x4 av[1][2]; zacc(av);
        {
            const uint16_t* ap = SH + r16*136 + g*8;
            const uint16_t* bbase = W + W_SKIPG + (size_t)(w*16 + r16)*128 + g*8;
            short8 ring[4];
            #pragma unroll
            for (int t=0;t<4;++t) ring[t] = *(const short8*)(bbase + t*32);
            #pragma unroll
            for (int s=0;s<4;++s){
                short8 af[2];
                #pragma unroll
                for (int mt=0;mt<2;++mt) af[mt] = *(const short8*)(ap + mt*16*136 + s*32);
                short8 bf = ring[s];
                #pragma unroll
                for (int mt=0;mt<2;++mt)
                    av[0][mt] = __builtin_amdgcn_mfma_f32_16x16x32_bf16(af[mt], bf, av[0][mt],0,0,0);
            }
        }
        int n = w*16 + r16;
        #pragma unroll
        for (int mt=0;mt<2;++mt)
            #pragma unroll
            for (int q=0;q<4;++q){
                int mrow = mt*16+g*4+q;
                ACT[mrow*AP+n] = f2bf(skk[mt][q]*sigm(av[0][mt][q]));
            }
    }
    __syncthreads();
    // ======== sig: waves 0-3 (Npad=64), valid n<40 ========
    if (w < 4){
        f32x4 av[1][2]; zacc(av);
        wgemm4<4,1>(av, W+W_SIG, 128, ACT, AP, w,r16,g);
        int n = w*16 + r16;
        if (n < 40){
            #pragma unroll
            for (int mt=0;mt<2;++mt)
                #pragma unroll
                for (int q=0;q<4;++q){
                    int mrow = mt*16+g*4+q;
                    float sv = tanh_f(av[0][mt][q]) * GAIN[mrow];
                    out[OSIG + (long)(row0+mrow)*40 + n] = sv;
                    out[OEXC + (long)(row0+mrow)*256 + 216 + n] = sv;
                }
        }
    }
}

extern "C" void kernel_launch(void* const* d_in, const int* in_sizes, int n_in,
                              void* d_out, int out_size, void* d_ws, size_t ws_size,
                              hipStream_t stream) {
    const float* cond      = (const float*)d_in[0];
    const float* prev_pred = (const float*)d_in[1];
    const float* exc_mem   = (const float*)d_in[2];
    const float* period    = (const float*)d_in[3];
    const float* s1        = (const float*)d_in[4];
    const float* s2        = (const float*)d_in[5];
    const float* s3        = (const float*)d_in[6];
    const float* s4        = (const float*)d_in[7];
    const float* w_gain    = (const float*)d_in[8];
    const float* b_gain    = (const float*)d_in[9];
    const float* w_fwc0    = (const float*)d_in[10];
    const float* w_fwc0_glu= (const float*)d_in[11];
    const float* wih1      = (const float*)d_in[12];
    const float* whh1      = (const float*)d_in[13];
    const float* wglu1     = (const float*)d_in[14];
    const float* wih2      = (const float*)d_in[15];
    const float* whh2      = (const float*)d_in[16];
    const float* wglu2     = (const float*)d_in[17];
    const float* wih3      = (const float*)d_in[18];
    const float* whh3      = (const float*)d_in[19];
    const float* wglu3     = (const float*)d_in[20];
    const float* w_skip    = (const float*)d_in[21];
    const float* w_skip_glu= (const float*)d_in[22];
    const float* w_sig     = (const float*)d_in[23];
    const float* w_pg      = (const float*)d_in[24];
    const float* b_pg      = (const float*)d_in[25];
    float* out = (float*)d_out;
    uint16_t* wsbf = (uint16_t*)d_ws;

    PrepArgs pa;
    pa.s[0]=w_fwc0; pa.s[1]=w_fwc0_glu; pa.s[2]=wih1; pa.s[3]=whh1; pa.s[4]=wglu1;
    pa.s[5]=wih2; pa.s[6]=whh2; pa.s[7]=wglu2; pa.s[8]=wih3; pa.s[9]=whh3;
    pa.s[10]=wglu3; pa.s[11]=w_skip; pa.s[12]=w_skip_glu; pa.s[13]=w_pg; pa.s[14]=w_sig;

    hipLaunchKernelGGL(prep_kernel, dim3(3856), dim3(64), 0, stream, pa, wsbf);
    hipLaunchKernelGGL(fargan_mfma, dim3(1024), dim3(512), 0, stream,
        cond, prev_pred, exc_mem, period, s1, s2, s3, s4,
        w_gain, b_gain, b_pg, wsbf, out);
}

// Round 13
// 261.929 us; speedup vs baseline: 1.0387x; 1.0387x over previous
//
#include <hip/hip_runtime.h>
#include <hip/hip_bf16.h>
#include <cstdint>
#include <cmath>

#define BTOT 32768L
#define OSIG 0L
#define OEXC (BTOT*40L)
#define OPREV (OEXC + BTOT*256L)
#define OH1 (OPREV + BTOT*256L)
#define OH2 (OH1 + BTOT*160L)
#define OH3 (OH2 + BTOT*128L)
#define ONS4 (OH3 + BTOT*128L)

typedef __attribute__((ext_vector_type(8))) short short8;
typedef __attribute__((ext_vector_type(4))) short short4v;
typedef __attribute__((ext_vector_type(4))) float f32x4;

#define AP 968   // ACT pitch (bf16 elems)

// ACT column map: identical to R10 lifetime audit; 32 rows.
// ws layout (bf16). All blocks [Npad][KP], row-major, zero-padded.
#define W_F0     0L        // [192][352]
#define W_F0G    67584L    // [192][192]
#define W_PG     104448L   // [16][192]
#define W_IH1R   107520L   // [192][288]
#define W_IH1Z   162816L
#define W_IH1N   218112L
#define W_HH1R   273408L   // [192][192]
#define W_HH1Z   310272L
#define W_HH1N   347136L
#define W_GLU1   384000L   // [192][192]
#define W_IH2R   420864L   // [128][256]
#define W_IH2Z   453632L
#define W_IH2N   486400L
#define W_HH2R   519168L   // [128][128]
#define W_HH2Z   535552L
#define W_HH2N   551936L
#define W_GLU2   568320L   // [128][128]
#define W_IH3R   584704L   // [128][224]
#define W_IH3Z   613376L
#define W_IH3N   642048L
#define W_HH3R   670720L   // [128][128]
#define W_HH3Z   687104L
#define W_HH3N   703488L
#define W_GLU3   719872L   // [128][128]
#define W_SKIP   736256L   // [128][960] column-permuted to ACT map
#define W_SKIPG  859136L   // [128][128]
#define W_SIG    875520L   // [64][128]

__device__ __forceinline__ float sigm(float x){ return 1.0f/(1.0f+__expf(-x)); }
__device__ __forceinline__ float tanh_f(float x){
    float e = __expf(2.0f*x);
    return 1.0f - 2.0f/(e+1.0f);
}
__device__ __forceinline__ uint16_t f2bf(float x){
    __hip_bfloat16 h = __float2bfloat16(x);
    return *(uint16_t*)&h;
}
__device__ __forceinline__ float bf2f(uint16_t h){
    union { float f; uint32_t u; } v; v.u = ((uint32_t)h)<<16;
    return v.f;
}
__device__ __forceinline__ short4v pack4(float4 v){
    short4v r;
    r.x=(short)f2bf(v.x); r.y=(short)f2bf(v.y); r.z=(short)f2bf(v.z); r.w=(short)f2bf(v.w);
    return r;
}

// ---------------- prep: fp32 weights -> padded bf16 blocks in ws ----------------
struct PrepArgs { const float* s[15]; };

__global__ __launch_bounds__(64) void prep_kernel(PrepArgs pa, uint16_t* dst){
    static const long J[27][8] = {
        {0,  0,192,328,352,192, W_F0,   0},
        {1,  0,192,192,192,192, W_F0G,  0},
        {13, 0,  4,192,192, 16, W_PG,   0},
        {2,  0,160,272,288,192, W_IH1R, 0},
        {2,160,160,272,288,192, W_IH1Z, 0},
        {2,320,160,272,288,192, W_IH1N, 0},
        {3,  0,160,160,192,192, W_HH1R, 0},
        {3,160,160,160,192,192, W_HH1Z, 0},
        {3,320,160,160,192,192, W_HH1N, 0},
        {4,  0,160,160,192,192, W_GLU1, 0},
        {5,  0,128,240,256,128, W_IH2R, 0},
        {5,128,128,240,256,128, W_IH2Z, 0},
        {5,256,128,240,256,128, W_IH2N, 0},
        {6,  0,128,128,128,128, W_HH2R, 0},
        {6,128,128,128,128,128, W_HH2Z, 0},
        {6,256,128,128,128,128, W_HH2N, 0},
        {7,  0,128,128,128,128, W_GLU2, 0},
        {8,  0,128,208,224,128, W_IH3R, 0},
        {8,128,128,208,224,128, W_IH3Z, 0},
        {8,256,128,208,224,128, W_IH3N, 0},
        {9,  0,128,128,128,128, W_HH3R, 0},
        {9,128,128,128,128,128, W_HH3Z, 0},
        {9,256,128,128,128,128, W_HH3N, 0},
        {10, 0,128,128,128,128, W_GLU3, 0},
        {11, 0,128,688,960,128, W_SKIP, 1},
        {12, 0,128,128,128,128, W_SKIPG,0},
        {14, 0, 40,128,128, 64, W_SIG,  0},
    };
    long row = blockIdx.x;
    int j = 0;
    while (row >= J[j][5]) { row -= J[j][5]; ++j; }
    const float* src = pa.s[J[j][0]];
    const long ro = J[j][1], N = J[j][2], K = J[j][3], KP = J[j][4];
    const int type = (int)J[j][7];
    uint16_t* d = dst + J[j][6] + row*KP;
    for (long k = threadIdx.x; k < KP; k += 64){
        float v = 0.0f;
        if (row < N){
            if (type == 0){
                if (k < K) v = src[(ro+row)*K + k];
            } else {
                long s = -1;
                if (k < 192) s = 416 + k;                        // fwc0
                else if (k >= 232 && k < 272) s = 648 + (k-232); // prev
                else if (k >= 288 && k < 448) s = (k-288);       // g1
                else if (k >= 544 && k < 672) s = 160 + (k-544); // g2
                else if (k >= 768 && k < 896) s = 288 + (k-768); // g3
                else if (k >= 896 && k < 936) s = 608 + (k-896); // pf4
                if (s >= 0) v = src[row*688 + s];
            }
        }
        d[k] = f2bf(v);
    }
}

// ---------------- dual-m-tile wave GEMM, 4 waves, n-tiles {w+4i}, 6-deep ring ----------------
template<int KS, int CNT>
__device__ __forceinline__ void wgemm4(f32x4 (&acc)[CNT][2],
    const uint16_t* __restrict__ Bw, int KP,
    const uint16_t* A, int P, int w, int r16, int g)
{
    constexpr int T = KS*CNT;
    constexpr int PF = (T < 6) ? T : 6;
    const uint16_t* ap = A + r16*P + g*8;
    const uint16_t* bbase = Bw + (size_t)(w*16 + r16)*KP + g*8;
    short8 ring[PF];
    #pragma unroll
    for (int t=0;t<PF;++t)
        ring[t] = *(const short8*)(bbase + (size_t)(t%CNT)*64*KP + (size_t)(t/CNT)*32);
    short8 af[2];
    #pragma unroll
    for (int t=0;t<T;++t){
        const int s = t/CNT, i = t%CNT;
        if (i==0){
            #pragma unroll
            for (int mt=0;mt<2;++mt) af[mt] = *(const short8*)(ap + mt*16*P + s*32);
        }
        short8 bf = ring[t%PF];
        if (t+PF < T)
            ring[t%PF] = *(const short8*)(bbase + (size_t)((t+PF)%CNT)*64*KP + (size_t)((t+PF)/CNT)*32);
        #pragma unroll
        for (int mt=0;mt<2;++mt)
            acc[i][mt] = __builtin_amdgcn_mfma_f32_16x16x32_bf16(af[mt], bf, acc[i][mt],0,0,0);
    }
}
template<int CNT> __device__ __forceinline__ void zacc(f32x4 (&a)[CNT][2]){
    f32x4 z4 = {0.f,0.f,0.f,0.f};
    #pragma unroll
    for (int i=0;i<CNT;++i){
        #pragma unroll
        for (int mt=0;mt<2;++mt) a[i][mt]=z4;
    }
}

// ---------------- GRU1 merged h-phase (H=160, CNT=3) ----------------
__device__ __forceinline__ void gru1_h(const uint16_t* __restrict__ W, uint16_t* ACTp,
    const float* __restrict__ s1g, float* __restrict__ out,
    float (&hk)[3][2][4], int row0, int w, int r16, int g)
{
    f32x4 gx[3][2], gh[3][2], ra[3][2], za[3][2];
    zacc(gx); zacc(gh); zacc(ra); zacc(za);
    wgemm4<9,3>(gx, W+W_IH1N, 288, ACTp,     AP, w,r16,g);
    wgemm4<9,3>(ra, W+W_IH1R, 288, ACTp,     AP, w,r16,g);
    wgemm4<9,3>(za, W+W_IH1Z, 288, ACTp,     AP, w,r16,g);
    wgemm4<6,3>(gh, W+W_HH1N, 192, ACTp+544, AP, w,r16,g);
    wgemm4<6,3>(ra, W+W_HH1R, 192, ACTp+544, AP, w,r16,g);
    wgemm4<6,3>(za, W+W_HH1Z, 192, ACTp+544, AP, w,r16,g);
    #pragma unroll
    for (int i=0;i<3;++i){
        int n = (w+4*i)*16 + r16;
        #pragma unroll
        for (int mt=0;mt<2;++mt){
            #pragma unroll
            for (int q=0;q<4;++q){
                int mrow = mt*16+g*4+q;
                float h = 0.f;
                if (n < 160){
                    float hpv = s1g[(long)(row0+mrow)*160 + n];
                    float r = sigm(ra[i][mt][q]);
                    float z = sigm(za[i][mt][q]);
                    float nn = tanh_f(gx[i][mt][q] + r*gh[i][mt][q]);
                    h = (1.f-z)*nn + z*hpv;
                    out[OH1 + (long)(row0+mrow)*160 + n] = h;
                }
                hk[i][mt][q] = h;
                ACTp[mrow*AP+768+n] = f2bf(h);   // HB1 (h; zeros n>=160)
            }
        }
    }
}
__device__ __forceinline__ void glu1(const uint16_t* __restrict__ W, uint16_t* ACTp,
                                     float (&hk)[3][2][4], int w, int r16, int g){
    f32x4 gl[3][2];
    zacc(gl);
    wgemm4<6,3>(gl, W+W_GLU1, 192, ACTp+768, AP, w,r16,g);
    #pragma unroll
    for (int i=0;i<3;++i){
        int n = (w+4*i)*16 + r16;
        if (n < 160){
            #pragma unroll
            for (int mt=0;mt<2;++mt)
                #pragma unroll
                for (int q=0;q<4;++q){
                    int mrow = mt*16+g*4+q;
                    ACTp[mrow*AP + 288 + n] = f2bf(hk[i][mt][q]*sigm(gl[i][mt][q]));  // g1
                }
        }
    }
}

// ---------------- GRU2/3 merged h-phase (H=128, CNT=2) ----------------
template<int KSX, int KSH>
__device__ __forceinline__ void gru23_h(
    const uint16_t* __restrict__ Wxr, const uint16_t* __restrict__ Wxz, const uint16_t* __restrict__ Wxn, int KPX,
    const uint16_t* __restrict__ Whr, const uint16_t* __restrict__ Whz, const uint16_t* __restrict__ Whn, int KPH,
    const uint16_t* XA, const uint16_t* HA, int HAP,
    const float* __restrict__ sg, float* __restrict__ outp, long obase,
    uint16_t* HBdst, int HBpitch,
    float (&hk)[2][2][4], int row0, int w, int r16, int g)
{
    f32x4 gx[2][2], gh[2][2], ra[2][2], za[2][2];
    zacc(gx); zacc(gh); zacc(ra); zacc(za);
    wgemm4<KSX,2>(gx, Wxn, KPX, XA, AP, w,r16,g);
    wgemm4<KSX,2>(ra, Wxr, KPX, XA, AP, w,r16,g);
    wgemm4<KSX,2>(za, Wxz, KPX, XA, AP, w,r16,g);
    wgemm4<KSH,2>(gh, Whn, KPH, HA, HAP, w,r16,g);
    wgemm4<KSH,2>(ra, Whr, KPH, HA, HAP, w,r16,g);
    wgemm4<KSH,2>(za, Whz, KPH, HA, HAP, w,r16,g);
    #pragma unroll
    for (int i=0;i<2;++i){
        int n = (w+4*i)*16 + r16;
        #pragma unroll
        for (int mt=0;mt<2;++mt){
            #pragma unroll
            for (int q=0;q<4;++q){
                int mrow = mt*16+g*4+q;
                float hpv = sg[(long)(row0+mrow)*128 + n];
                float r = sigm(ra[i][mt][q]), z = sigm(za[i][mt][q]);
                float nn = tanh_f(gx[i][mt][q] + r*gh[i][mt][q]);
                float h = (1.f-z)*nn + z*hpv;
                outp[obase + (long)(row0+mrow)*128 + n] = h;
                hk[i][mt][q] = h;
                if (HBdst) HBdst[mrow*HBpitch + n] = f2bf(h);
            }
        }
    }
}

// ---------------- main kernel: 32 rows / block, 256 threads, 2 blocks/CU, 256-reg budget ----------------
extern "C" __global__ __launch_bounds__(256, 2)
void fargan_mfma(const float* __restrict__ cond, const float* __restrict__ prev_pred,
                 const float* __restrict__ exc_mem, const float* __restrict__ period,
                 const float* __restrict__ s1, const float* __restrict__ s2,
                 const float* __restrict__ s3, const float* __restrict__ s4,
                 const float* __restrict__ w_gain, const float* __restrict__ b_gain,
                 const float* __restrict__ b_pg,
                 const uint16_t* __restrict__ W, float* __restrict__ out)
{
    __shared__ __align__(16) uint16_t ACT[32*AP];
    __shared__ __align__(16) uint16_t SH[32*136];
    __shared__ uint16_t FPITCHb[32*40];
    __shared__ float GAIN[32];
    __shared__ float PGs[32][4];

    const int tid = threadIdx.x;
    const int row0 = blockIdx.x * 32;
    const int w = tid >> 6, l = tid & 63, r16 = l & 15, g = l >> 4;
    const int rr = tid >> 3, c8 = tid & 7;
    const long grow = row0 + rr;

    // ======== stage A (float4-vectorized; 8 threads/row) ========
    const float* exc_row = exc_mem + grow*256;

    float a0 = 0.f;
    {
        const float4* c4 = (const float4*)(cond + grow*80);
        const float4* g4 = (const float4*)w_gain;
        float4* on4 = (float4*)(out + ONS4 + grow*164);
        for (int i=c8;i<20;i+=8){
            float4 cv = c4[i], gv = g4[i];
            a0 += cv.x*gv.x + cv.y*gv.y + cv.z*gv.z + cv.w*gv.w;
            *(short4v*)&ACT[rr*AP + 164 + 4*i] = pack4(cv);
            on4[i] = cv;
        }
    }
    a0 += __shfl_xor(a0,4,8); a0 += __shfl_xor(a0,2,8); a0 += __shfl_xor(a0,1,8);
    float gn = 0.2f + 0.8f*sigm(a0 + b_gain[0]);
    if (!(gn==gn)) gn = 1.0f;
    gn = fminf(fmaxf(gn, 0.001f), 20.0f);
    float inv = 1.0f/(1e-5f+gn);
    if (c8==0) GAIN[rr] = gn;

    float p = period[grow];
    p = (fabsf(p) <= 3.0e38f) ? p : 128.0f;
    p = fminf(fmaxf(p, 32.0f), 255.0f);

    for (int e=c8;e<44;e+=8){
        float idxf = 254.0f - p + (float)e;
        float idx0 = floorf(idxf);
        float al = fminf(fmaxf(idxf-idx0, 0.f), 1.f);
        int i0 = (int)fminf(fmaxf(idx0, 0.f), 255.f);
        int i1 = (int)fminf(fmaxf(idx0+1.f, 0.f), 255.f);
        float pr = (1.f-al)*exc_row[i0] + al*exc_row[i1];
        float pn = pr*inv;
        ACT[rr*AP + 244 + e] = f2bf(pn);             // XCAT pred_n
        out[ONS4 + grow*164 + 80 + e] = pn;
        if (e>=2 && e<42){
            out[OPREV + grow*256 + 216 + (e-2)] = pr;
            FPITCHb[rr*40 + (e-2)] = f2bf(pn);
        }
    }
    {
        const float4* pv4 = (const float4*)(exc_row + 216);
        float4* onp = (float4*)(out + ONS4 + grow*164 + 124);
        for (int i=c8;i<10;i+=8){
            float4 v = pv4[i];
            v.x*=inv; v.y*=inv; v.z*=inv; v.w*=inv;
            *(short4v*)&ACT[rr*AP + 288 + 4*i] = pack4(v);   // XCAT prev (stable until GLU1)
            onp[i] = v;
        }
    }
    {
        const float4* s44 = (const float4*)(s4 + grow*164);
        for (int i=c8;i<41;i+=8)
            *(short4v*)&ACT[rr*AP + 4*i] = pack4(s44[i]);    // XCAT s4
        const float4* s14 = (const float4*)(s1 + grow*160);
        for (int i=c8;i<40;i+=8)
            *(short4v*)&ACT[rr*AP + 544 + 4*i] = pack4(s14[i]);  // s1-state
    }
    for (int i=328+c8;i<352;i+=8) ACT[rr*AP + i] = 0;            // XCAT pad
    for (int i=704+c8;i<736;i+=8) ACT[rr*AP + i] = 0;            // s1 pad
    {
        const float4* pp4 = (const float4*)(prev_pred + grow*256 + 40);
        const float4* ex4 = (const float4*)(exc_row + 40);
        float4* op4 = (float4*)(out + OPREV + grow*256);
        float4* oe4 = (float4*)(out + OEXC + grow*256);
        for (int i=c8;i<54;i+=8){ op4[i] = pp4[i]; oe4[i] = ex4[i]; }
    }
    __syncthreads();

    float fwk[3][2][4];

    // ======== fwc0: tanh(XCAT[0,352) @ W_F0^T) -> FWRAW @ [352,544), CNT=3 ========
    {
        f32x4 av[3][2]; zacc(av);
        wgemm4<11,3>(av, W+W_F0, 352, ACT, AP, w,r16,g);
        #pragma unroll
        for (int i=0;i<3;++i){
            int n = (w+4*i)*16 + r16;
            #pragma unroll
            for (int mt=0;mt<2;++mt)
                #pragma unroll
                for (int q=0;q<4;++q){
                    int mrow = mt*16+g*4+q;
                    float t = tanh_f(av[i][mt][q]);
                    fwk[i][mt][q] = t;
                    ACT[mrow*AP+352+n] = f2bf(t);
                }
        }
    }
    __syncthreads();

    // ======== f0g GLU -> fwc0 @ [0,192), CNT=3 ========
    {
        f32x4 av[3][2]; zacc(av);
        wgemm4<6,3>(av, W+W_F0G, 192, ACT+352, AP, w,r16,g);
        #pragma unroll
        for (int i=0;i<3;++i){
            int n = (w+4*i)*16 + r16;
            #pragma unroll
            for (int mt=0;mt<2;++mt)
                #pragma unroll
                for (int q=0;q<4;++q){
                    int mrow = mt*16+g*4+q;
                    ACT[mrow*AP+n] = f2bf(fwk[i][mt][q]*sigm(av[i][mt][q]));
                }
        }
    }
    __syncthreads();

    // ======== pitch gain (all waves redundant; wave0 writes) ========
    {
        f32x4 av[1][2]; zacc(av);
        wgemm4<6,1>(av, W+W_PG, 192, ACT, AP, 0, r16, g);
        if (w==0 && r16<4){
            float bp = b_pg[r16];
            #pragma unroll
            for (int mt=0;mt<2;++mt)
                #pragma unroll
                for (int q=0;q<4;++q)
                    PGs[mt*16+g*4+q][r16] = sigm(av[0][mt][q] + bp);
        }
    }
    __syncthreads();

    // ======== pf1 @[192,232); prev -> stable [232,272) ========
    for (int i=c8;i<40;i+=8){
        ACT[rr*AP+192+i] = f2bf(PGs[rr][0]*bf2f(FPITCHb[rr*40+i]));
        ACT[rr*AP+232+i] = ACT[rr*AP+288+i];
    }
    __syncthreads();

    // ======== GRU1 merged h-phase ========
    float hk1[3][2][4];
    gru1_h(W, ACT, s1, out, hk1, row0, w,r16,g);
    __syncthreads();

    // ======== GLU1 -> g1 @[288,448); stage s2 -> [544,672), pf2@448, prev2@488, z@528 ========
    glu1(W, ACT, hk1, w,r16,g);
    {
        const float4* s24 = (const float4*)(s2 + grow*128);
        for (int i=c8;i<32;i+=8)
            *(short4v*)&ACT[rr*AP + 544 + 4*i] = pack4(s24[i]);
    }
    for (int i=c8;i<40;i+=8){
        ACT[rr*AP+448+i] = f2bf(PGs[rr][1]*bf2f(FPITCHb[rr*40+i]));
        ACT[rr*AP+488+i] = ACT[rr*AP+232+i];
    }
    for (int i=528+c8;i<544;i+=8) ACT[rr*AP+i] = 0;
    __syncthreads();

    // ======== GRU2: x=[288,544) K256, h=[544,672); HB2 -> [768,896) ========
    float hk[2][2][4];
    gru23_h<8,4>(W+W_IH2R, W+W_IH2Z, W+W_IH2N, 256,
                 W+W_HH2R, W+W_HH2Z, W+W_HH2N, 128,
                 ACT+288, ACT+544, AP, s2, out, OH2,
                 ACT+768, AP, hk, row0, w,r16,g);
    __syncthreads();

    // ======== GLU2 -> g2 @[544,672); stage s3 -> SH, pf3@672, prev3@712, z@752 ========
    {
        f32x4 gl[2][2]; zacc(gl);
        wgemm4<4,2>(gl, W+W_GLU2, 128, ACT+768, AP, w,r16,g);
        #pragma unroll
        for (int i=0;i<2;++i){
            int n = (w+4*i)*16 + r16;
            #pragma unroll
            for (int mt=0;mt<2;++mt)
                #pragma unroll
                for (int q=0;q<4;++q){
                    int mrow = mt*16+g*4+q;
                    ACT[mrow*AP+544+n] = f2bf(hk[i][mt][q]*sigm(gl[i][mt][q]));
                }
        }
    }
    {
        const float4* s34 = (const float4*)(s3 + grow*128);
        for (int i=c8;i<32;i+=8)
            *(short4v*)&SH[rr*136 + 4*i] = pack4(s34[i]);
    }
    for (int i=c8;i<40;i+=8){
        ACT[rr*AP+672+i] = f2bf(PGs[rr][2]*bf2f(FPITCHb[rr*40+i]));
        ACT[rr*AP+712+i] = ACT[rr*AP+232+i];
    }
    for (int i=752+c8;i<768;i+=8) ACT[rr*AP+i] = 0;
    __syncthreads();

    // ======== GRU3: x=[544,768) K224, h=SH (pitch 136); hk kept in regs ========
    gru23_h<7,4>(W+W_IH3R, W+W_IH3Z, W+W_IH3N, 224,
                 W+W_HH3R, W+W_HH3Z, W+W_HH3N, 128,
                 ACT+544, SH, 136, s3, out, OH3,
                 (uint16_t*)nullptr, 0, hk, row0, w,r16,g);
    __syncthreads();

    // ======== HB3 -> SH (s3 dead) ========
    #pragma unroll
    for (int i=0;i<2;++i){
        int n = (w+4*i)*16 + r16;
        #pragma unroll
        for (int mt=0;mt<2;++mt)
            #pragma unroll
            for (int q=0;q<4;++q)
                SH[(mt*16+g*4+q)*136 + n] = f2bf(hk[i][mt][q]);
    }
    __syncthreads();

    // ======== GLU3 (reads SH, pitch 136) -> g3 @[768,896); pf4@896 ========
    {
        f32x4 gl[2][2]; zacc(gl);
        wgemm4<4,2>(gl, W+W_GLU3, 128, SH, 136, w,r16,g);
        #pragma unroll
        for (int i=0;i<2;++i){
            int n = (w+4*i)*16 + r16;
            #pragma unroll
            for (int mt=0;mt<2;++mt)
                #pragma unroll
                for (int q=0;q<4;++q){
                    int mrow = mt*16+g*4+q;
                    ACT[mrow*AP+768+n] = f2bf(hk[i][mt][q]*sigm(gl[i][mt][q]));
                }
        }
    }
    for (int i=c8;i<40;i+=8)
        ACT[rr*AP+896+i] = f2bf(PGs[rr][3]*bf2f(FPITCHb[rr*40+i]));
    __syncthreads();

    // ======== skip: tanh(ACT[0,960) @ W_SKIP^T) -> SK @ SH, CNT=2 ========
    float skk[2][2][4];
    {
        f32x4 av[2][2]; zacc(av);
        wgemm4<30,2>(av, W+W_SKIP, 960, ACT, AP, w,r16,g);
        #pragma unroll
        for (int i=0;i<2;++i){
            int n = (w+4*i)*16 + r16;
            #pragma unroll
            for (int mt=0;mt<2;++mt)
                #pragma unroll
                for (int q=0;q<4;++q){
                    int mrow = mt*16+g*4+q;
                    float t = tanh_f(av[i][mt][q]);
                    skk[i][mt][q] = t;
                    SH[mrow*136+n] = f2bf(t);
                }
        }
    }
    __syncthreads();
    // ======== skip GLU (reads SH, pitch 136) -> SK2 @ ACT[0,128) ========
    {
        f32x4 av[2][2]; zacc(av);
        wgemm4<4,2>(av, W+W_SKIPG, 128, SH, 136, w,r16,g);
        #pragma unroll
        for (int i=0;i<2;++i){
            int n = (w+4*i)*16 + r16;
            #pragma unroll
            for (int mt=0;mt<2;++mt)
                #pragma unroll
                for (int q=0;q<4;++q){
                    int mrow = mt*16+g*4+q;
                    ACT[mrow*AP+n] = f2bf(skk[i][mt][q]*sigm(av[i][mt][q]));
                }
        }
    }
    __syncthreads();
    // ======== sig: Npad=64, 4 waves × 1 tile, valid n<40 ========
    {
        f32x4 av[1][2]; zacc(av);
        wgemm4<4,1>(av, W+W_SIG, 128, ACT, AP, w,r16,g);
        int n = w*16 + r16;
        if (n < 40){
            #pragma unroll
            for (int mt=0;mt<2;++mt)
                #pragma unroll
                for (int q=0;q<4;++q){
                    int mrow = mt*16+g*4+q;
                    float sv = tanh_f(av[0][mt][q]) * GAIN[mrow];
                    out[OSIG + (long)(row0+mrow)*40 + n] = sv;
                    out[OEXC + (long)(row0+mrow)*256 + 216 + n] = sv;
                }
        }
    }
}

extern "C" void kernel_launch(void* const* d_in, const int* in_sizes, int n_in,
                              void* d_out, int out_size, void* d_ws, size_t ws_size,
                              hipStream_t stream) {
    const float* cond      = (const float*)d_in[0];
    const float* prev_pred = (const float*)d_in[1];
    const float* exc_mem   = (const float*)d_in[2];
    const float* period    = (const float*)d_in[3];
    const float* s1        = (const float*)d_in[4];
    const float* s2        = (const float*)d_in[5];
    const float* s3        = (const float*)d_in[6];
    const float* s4        = (const float*)d_in[7];
    const float* w_gain    = (const float*)d_in[8];
    const float* b_gain    = (const float*)d_in[9];
    const float* w_fwc0    = (const float*)d_in[10];
    const float* w_fwc0_glu= (const float*)d_in[11];
    const float* wih1      = (const float*)d_in[12];
    const float* whh1      = (const float*)d_in[13];
    const float* wglu1     = (const float*)d_in[14];
    const float* wih2      = (const float*)d_in[15];
    const float* whh2      = (const float*)d_in[16];
    const float* wglu2     = (const float*)d_in[17];
    const float* wih3      = (const float*)d_in[18];
    const float* whh3      = (const float*)d_in[19];
    const float* wglu3     = (const float*)d_in[20];
    const float* w_skip    = (const float*)d_in[21];
    const float* w_skip_glu= (const float*)d_in[22];
    const float* w_sig     = (const float*)d_in[23];
    const float* w_pg      = (const float*)d_in[24];
    const float* b_pg      = (const float*)d_in[25];
    float* out = (float*)d_out;
    uint16_t* wsbf = (uint16_t*)d_ws;

    PrepArgs pa;
    pa.s[0]=w_fwc0; pa.s[1]=w_fwc0_glu; pa.s[2]=wih1; pa.s[3]=whh1; pa.s[4]=wglu1;
    pa.s[5]=wih2; pa.s[6]=whh2; pa.s[7]=wglu2; pa.s[8]=wih3; pa.s[9]=whh3;
    pa.s[10]=wglu3; pa.s[11]=w_skip; pa.s[12]=w_skip_glu; pa.s[13]=w_pg; pa.s[14]=w_sig;

    hipLaunchKernelGGL(prep_kernel, dim3(3856), dim3(64), 0, stream, pa, wsbf);
    hipLaunchKernelGGL(fargan_mfma, dim3(1024), dim3(256), 0, stream,
        cond, prev_pred, exc_mem, period, s1, s2, s3, s4,
        w_gain, b_gain, b_pg, wsbf, out);
}

// Round 14
// 229.968 us; speedup vs baseline: 1.1831x; 1.1390x over previous
//
#include <hip/hip_runtime.h>
#include <hip/hip_bf16.h>
#include <cstdint>
#include <cmath>

#define BTOT 32768L
#define OSIG 0L
#define OEXC (BTOT*40L)
#define OPREV (OEXC + BTOT*256L)
#define OH1 (OPREV + BTOT*256L)
#define OH2 (OH1 + BTOT*160L)
#define OH3 (OH2 + BTOT*128L)
#define ONS4 (OH3 + BTOT*128L)

typedef __attribute__((ext_vector_type(8))) short short8;
typedef __attribute__((ext_vector_type(4))) short short4v;
typedef __attribute__((ext_vector_type(4))) float f32x4;

#define AP 968   // ACT pitch (bf16 elems)

// ACT column map: identical to R10 lifetime audit; 64 rows.
// ws layout (bf16). All blocks [Npad][KP], row-major, zero-padded.
#define W_F0     0L        // [192][352]
#define W_F0G    67584L    // [192][192]
#define W_PG     104448L   // [16][192]
#define W_IH1R   107520L   // [192][288]
#define W_IH1Z   162816L
#define W_IH1N   218112L
#define W_HH1R   273408L   // [192][192]
#define W_HH1Z   310272L
#define W_HH1N   347136L
#define W_GLU1   384000L   // [192][192]
#define W_IH2R   420864L   // [128][256]
#define W_IH2Z   453632L
#define W_IH2N   486400L
#define W_HH2R   519168L   // [128][128]
#define W_HH2Z   535552L
#define W_HH2N   551936L
#define W_GLU2   568320L   // [128][128]
#define W_IH3R   584704L   // [128][224]
#define W_IH3Z   613376L
#define W_IH3N   642048L
#define W_HH3R   670720L   // [128][128]
#define W_HH3Z   687104L
#define W_HH3N   703488L
#define W_GLU3   719872L   // [128][128]
#define W_SKIP   736256L   // [128][960] column-permuted to ACT map
#define W_SKIPG  859136L   // [128][128]
#define W_SIG    875520L   // [64][128]

__device__ __forceinline__ float sigm(float x){ return 1.0f/(1.0f+__expf(-x)); }
__device__ __forceinline__ float tanh_f(float x){
    float e = __expf(2.0f*x);
    return 1.0f - 2.0f/(e+1.0f);
}
__device__ __forceinline__ uint16_t f2bf(float x){
    __hip_bfloat16 h = __float2bfloat16(x);
    return *(uint16_t*)&h;
}
__device__ __forceinline__ float bf2f(uint16_t h){
    union { float f; uint32_t u; } v; v.u = ((uint32_t)h)<<16;
    return v.f;
}
__device__ __forceinline__ short4v pack4(float4 v){
    short4v r;
    r.x=(short)f2bf(v.x); r.y=(short)f2bf(v.y); r.z=(short)f2bf(v.z); r.w=(short)f2bf(v.w);
    return r;
}

// ---------------- prep: fp32 weights -> padded bf16 blocks in ws ----------------
struct PrepArgs { const float* s[15]; };

__global__ __launch_bounds__(64) void prep_kernel(PrepArgs pa, uint16_t* dst){
    static const long J[27][8] = {
        {0,  0,192,328,352,192, W_F0,   0},
        {1,  0,192,192,192,192, W_F0G,  0},
        {13, 0,  4,192,192, 16, W_PG,   0},
        {2,  0,160,272,288,192, W_IH1R, 0},
        {2,160,160,272,288,192, W_IH1Z, 0},
        {2,320,160,272,288,192, W_IH1N, 0},
        {3,  0,160,160,192,192, W_HH1R, 0},
        {3,160,160,160,192,192, W_HH1Z, 0},
        {3,320,160,160,192,192, W_HH1N, 0},
        {4,  0,160,160,192,192, W_GLU1, 0},
        {5,  0,128,240,256,128, W_IH2R, 0},
        {5,128,128,240,256,128, W_IH2Z, 0},
        {5,256,128,240,256,128, W_IH2N, 0},
        {6,  0,128,128,128,128, W_HH2R, 0},
        {6,128,128,128,128,128, W_HH2Z, 0},
        {6,256,128,128,128,128, W_HH2N, 0},
        {7,  0,128,128,128,128, W_GLU2, 0},
        {8,  0,128,208,224,128, W_IH3R, 0},
        {8,128,128,208,224,128, W_IH3Z, 0},
        {8,256,128,208,224,128, W_IH3N, 0},
        {9,  0,128,128,128,128, W_HH3R, 0},
        {9,128,128,128,128,128, W_HH3Z, 0},
        {9,256,128,128,128,128, W_HH3N, 0},
        {10, 0,128,128,128,128, W_GLU3, 0},
        {11, 0,128,688,960,128, W_SKIP, 1},
        {12, 0,128,128,128,128, W_SKIPG,0},
        {14, 0, 40,128,128, 64, W_SIG,  0},
    };
    long row = blockIdx.x;
    int j = 0;
    while (row >= J[j][5]) { row -= J[j][5]; ++j; }
    const float* src = pa.s[J[j][0]];
    const long ro = J[j][1], N = J[j][2], K = J[j][3], KP = J[j][4];
    const int type = (int)J[j][7];
    uint16_t* d = dst + J[j][6] + row*KP;
    for (long k = threadIdx.x; k < KP; k += 64){
        float v = 0.0f;
        if (row < N){
            if (type == 0){
                if (k < K) v = src[(ro+row)*K + k];
            } else {
                long s = -1;
                if (k < 192) s = 416 + k;                        // fwc0
                else if (k >= 232 && k < 272) s = 648 + (k-232); // prev
                else if (k >= 288 && k < 448) s = (k-288);       // g1
                else if (k >= 544 && k < 672) s = 160 + (k-544); // g2
                else if (k >= 768 && k < 896) s = 288 + (k-768); // g3
                else if (k >= 896 && k < 936) s = 608 + (k-896); // pf4
                if (s >= 0) v = src[row*688 + s];
            }
        }
        d[k] = f2bf(v);
    }
}

// ---------------- quad-m-tile wave GEMM with 12-deep B-load ring prefetch ----------------
template<int KS, int CNT>
__device__ __forceinline__ void wgemm4(f32x4 (&acc)[CNT][4],
    const uint16_t* __restrict__ Bw, int KP,
    const uint16_t* A, int P, int w, int r16, int g)
{
    constexpr int T = KS*CNT;
    constexpr int PF = (T < 12) ? T : 12;
    const uint16_t* ap = A + r16*P + g*8;
    const uint16_t* bbase = Bw + (size_t)(w*16 + r16)*KP + g*8;
    short8 ring[PF];
    #pragma unroll
    for (int t=0;t<PF;++t)
        ring[t] = *(const short8*)(bbase + (size_t)(t%CNT)*128*KP + (size_t)(t/CNT)*32);
    short8 af[4];
    #pragma unroll
    for (int t=0;t<T;++t){
        const int s = t/CNT, i = t%CNT;
        if (i==0){
            #pragma unroll
            for (int mt=0;mt<4;++mt) af[mt] = *(const short8*)(ap + mt*16*P + s*32);
        }
        short8 bf = ring[t%PF];
        if (t+PF < T)
            ring[t%PF] = *(const short8*)(bbase + (size_t)((t+PF)%CNT)*128*KP + (size_t)((t+PF)/CNT)*32);
        #pragma unroll
        for (int mt=0;mt<4;++mt)
            acc[i][mt] = __builtin_amdgcn_mfma_f32_16x16x32_bf16(af[mt], bf, acc[i][mt],0,0,0);
    }
}
template<int CNT> __device__ __forceinline__ void zacc(f32x4 (&a)[CNT][4]){
    f32x4 z4 = {0.f,0.f,0.f,0.f};
    #pragma unroll
    for (int i=0;i<CNT;++i){
        #pragma unroll
        for (int mt=0;mt<4;++mt) a[i][mt]=z4;
    }
}

// ---------------- GRU1 merged h-phase (H=160, x=[0,288) K288, h=[544,736) K192) ----------------
template<int CNT>
__device__ __forceinline__ void gru1_h(const uint16_t* __restrict__ W, uint16_t* ACTp,
    const float* __restrict__ s1g, float* __restrict__ out,
    float (&hk)[2][4][4], int row0, int w, int r16, int g)
{
    f32x4 gx[CNT][4], gh[CNT][4], ra[CNT][4], za[CNT][4];
    zacc(gx); zacc(gh); zacc(ra); zacc(za);
    wgemm4<9,CNT>(gx, W+W_IH1N, 288, ACTp,     AP, w,r16,g);
    wgemm4<9,CNT>(ra, W+W_IH1R, 288, ACTp,     AP, w,r16,g);
    wgemm4<9,CNT>(za, W+W_IH1Z, 288, ACTp,     AP, w,r16,g);
    wgemm4<6,CNT>(gh, W+W_HH1N, 192, ACTp+544, AP, w,r16,g);
    wgemm4<6,CNT>(ra, W+W_HH1R, 192, ACTp+544, AP, w,r16,g);
    wgemm4<6,CNT>(za, W+W_HH1Z, 192, ACTp+544, AP, w,r16,g);
    #pragma unroll
    for (int i=0;i<CNT;++i){
        int n = (w+8*i)*16 + r16;
        #pragma unroll
        for (int mt=0;mt<4;++mt){
            #pragma unroll
            for (int q=0;q<4;++q){
                int mrow = mt*16+g*4+q;
                float h = 0.f;
                if (n < 160){
                    float hpv = s1g[(long)(row0+mrow)*160 + n];
                    float r = sigm(ra[i][mt][q]);
                    float z = sigm(za[i][mt][q]);
                    float nn = tanh_f(gx[i][mt][q] + r*gh[i][mt][q]);
                    h = (1.f-z)*nn + z*hpv;
                    out[OH1 + (long)(row0+mrow)*160 + n] = h;
                }
                hk[i][mt][q] = h;
                ACTp[mrow*AP+768+n] = f2bf(h);   // HB1 (h; zeros n>=160)
            }
        }
    }
}
template<int CNT>
__device__ __forceinline__ void glu1(const uint16_t* __restrict__ W, uint16_t* ACTp,
                                     float (&hk)[2][4][4], int w, int r16, int g){
    f32x4 gl[CNT][4];
    zacc(gl);
    wgemm4<6,CNT>(gl, W+W_GLU1, 192, ACTp+768, AP, w,r16,g);
    #pragma unroll
    for (int i=0;i<CNT;++i){
        int n = (w+8*i)*16 + r16;
        if (n < 160){
            #pragma unroll
            for (int mt=0;mt<4;++mt)
                #pragma unroll
                for (int q=0;q<4;++q){
                    int mrow = mt*16+g*4+q;
                    ACTp[mrow*AP + 288 + n] = f2bf(hk[i][mt][q]*sigm(gl[i][mt][q]));  // g1
                }
        }
    }
}

// ---------------- GRU2/3 merged h-phase (H=128) ----------------
template<int KSX, int KSH>
__device__ __forceinline__ void gru23_h(
    const uint16_t* __restrict__ Wxr, const uint16_t* __restrict__ Wxz, const uint16_t* __restrict__ Wxn, int KPX,
    const uint16_t* __restrict__ Whr, const uint16_t* __restrict__ Whz, const uint16_t* __restrict__ Whn, int KPH,
    const uint16_t* XA, const uint16_t* HA, int HAP,
    const float* __restrict__ sg, float* __restrict__ outp, long obase,
    uint16_t* HBdst, int HBpitch,
    float (&hk)[4][4], int row0, int w, int r16, int g)
{
    const int n = w*16 + r16;
    f32x4 gx[1][4], gh[1][4], ra[1][4], za[1][4];
    zacc(gx); zacc(gh); zacc(ra); zacc(za);
    wgemm4<KSX,1>(gx, Wxn, KPX, XA, AP, w,r16,g);
    wgemm4<KSX,1>(ra, Wxr, KPX, XA, AP, w,r16,g);
    wgemm4<KSX,1>(za, Wxz, KPX, XA, AP, w,r16,g);
    wgemm4<KSH,1>(gh, Whn, KPH, HA, HAP, w,r16,g);
    wgemm4<KSH,1>(ra, Whr, KPH, HA, HAP, w,r16,g);
    wgemm4<KSH,1>(za, Whz, KPH, HA, HAP, w,r16,g);
    #pragma unroll
    for (int mt=0;mt<4;++mt){
        #pragma unroll
        for (int q=0;q<4;++q){
            int mrow = mt*16+g*4+q;
            float hpv = sg[(long)(row0+mrow)*128 + n];
            float r = sigm(ra[0][mt][q]), z = sigm(za[0][mt][q]);
            float nn = tanh_f(gx[0][mt][q] + r*gh[0][mt][q]);
            float h = (1.f-z)*nn + z*hpv;
            outp[obase + (long)(row0+mrow)*128 + n] = h;
            hk[mt][q] = h;
            if (HBdst) HBdst[mrow*HBpitch + n] = f2bf(h);
        }
    }
}

// ---------------- main kernel: 64 rows / block, 512 threads, 1 block/CU ----------------
extern "C" __global__ __launch_bounds__(512, 2)
void fargan_mfma(const float* __restrict__ cond, const float* __restrict__ prev_pred,
                 const float* __restrict__ exc_mem, const float* __restrict__ period,
                 const float* __restrict__ s1, const float* __restrict__ s2,
                 const float* __restrict__ s3, const float* __restrict__ s4,
                 const float* __restrict__ w_gain, const float* __restrict__ b_gain,
                 const float* __restrict__ b_pg,
                 const uint16_t* __restrict__ W, float* __restrict__ out)
{
    __shared__ __align__(16) uint16_t ACT[64*AP];
    __shared__ __align__(16) uint16_t SH[64*136];
    __shared__ uint16_t FPITCHb[64*40];
    __shared__ float GAIN[64];
    __shared__ float PGs[64][4];

    const int tid = threadIdx.x;
    const int row0 = blockIdx.x * 64;
    const int w = tid >> 6, l = tid & 63, r16 = l & 15, g = l >> 4;
    const int rr = tid >> 3, c8 = tid & 7;
    const long grow = row0 + rr;

    // ======== stage A (float4-vectorized) ========
    const float* exc_row = exc_mem + grow*256;

    float a0 = 0.f;
    {
        const float4* c4 = (const float4*)(cond + grow*80);
        const float4* g4 = (const float4*)w_gain;
        float4* on4 = (float4*)(out + ONS4 + grow*164);
        for (int i=c8;i<20;i+=8){
            float4 cv = c4[i], gv = g4[i];
            a0 += cv.x*gv.x + cv.y*gv.y + cv.z*gv.z + cv.w*gv.w;
            *(short4v*)&ACT[rr*AP + 164 + 4*i] = pack4(cv);
            on4[i] = cv;
        }
    }
    a0 += __shfl_xor(a0,4,8); a0 += __shfl_xor(a0,2,8); a0 += __shfl_xor(a0,1,8);
    float gn = 0.2f + 0.8f*sigm(a0 + b_gain[0]);
    if (!(gn==gn)) gn = 1.0f;
    gn = fminf(fmaxf(gn, 0.001f), 20.0f);
    float inv = 1.0f/(1e-5f+gn);
    if (c8==0) GAIN[rr] = gn;

    float p = period[grow];
    p = (fabsf(p) <= 3.0e38f) ? p : 128.0f;
    p = fminf(fmaxf(p, 32.0f), 255.0f);

    for (int e=c8;e<44;e+=8){
        float idxf = 254.0f - p + (float)e;
        float idx0 = floorf(idxf);
        float al = fminf(fmaxf(idxf-idx0, 0.f), 1.f);
        int i0 = (int)fminf(fmaxf(idx0, 0.f), 255.f);
        int i1 = (int)fminf(fmaxf(idx0+1.f, 0.f), 255.f);
        float pr = (1.f-al)*exc_row[i0] + al*exc_row[i1];
        float pn = pr*inv;
        ACT[rr*AP + 244 + e] = f2bf(pn);             // XCAT pred_n
        out[ONS4 + grow*164 + 80 + e] = pn;
        if (e>=2 && e<42){
            out[OPREV + grow*256 + 216 + (e-2)] = pr;
            FPITCHb[rr*40 + (e-2)] = f2bf(pn);
        }
    }
    {
        const float4* pv4 = (const float4*)(exc_row + 216);
        float4* onp = (float4*)(out + ONS4 + grow*164 + 124);
        for (int i=c8;i<10;i+=8){
            float4 v = pv4[i];
            v.x*=inv; v.y*=inv; v.z*=inv; v.w*=inv;
            *(short4v*)&ACT[rr*AP + 288 + 4*i] = pack4(v);   // XCAT prev (stable until GLU1)
            onp[i] = v;
        }
    }
    {
        const float4* s44 = (const float4*)(s4 + grow*164);
        for (int i=c8;i<41;i+=8)
            *(short4v*)&ACT[rr*AP + 4*i] = pack4(s44[i]);    // XCAT s4
        const float4* s14 = (const float4*)(s1 + grow*160);
        for (int i=c8;i<40;i+=8)
            *(short4v*)&ACT[rr*AP + 544 + 4*i] = pack4(s14[i]);  // s1-state
    }
    for (int i=328+c8;i<352;i+=8) ACT[rr*AP + i] = 0;            // XCAT pad
    for (int i=704+c8;i<736;i+=8) ACT[rr*AP + i] = 0;            // s1 pad
    {
        const float4* pp4 = (const float4*)(prev_pred + grow*256 + 40);
        const float4* ex4 = (const float4*)(exc_row + 40);
        float4* op4 = (float4*)(out + OPREV + grow*256);
        float4* oe4 = (float4*)(out + OEXC + grow*256);
        for (int i=c8;i<54;i+=8){ op4[i] = pp4[i]; oe4[i] = ex4[i]; }
    }
    __syncthreads();

    float fwk[2][4][4];

    // ======== fwc0: tanh(XCAT[0,352) @ W_F0^T) -> FWRAW @ [352,544) ========
    if (w < 4){
        f32x4 av[2][4]; zacc(av);
        wgemm4<11,2>(av, W+W_F0, 352, ACT, AP, w,r16,g);
        #pragma unroll
        for (int i=0;i<2;++i){
            int n = (w+8*i)*16 + r16;
            #pragma unroll
            for (int mt=0;mt<4;++mt)
                #pragma unroll
                for (int q=0;q<4;++q){
                    int mrow = mt*16+g*4+q;
                    float t = tanh_f(av[i][mt][q]);
                    fwk[i][mt][q] = t;
                    ACT[mrow*AP+352+n] = f2bf(t);
                }
        }
    } else {
        f32x4 av[1][4]; zacc(av);
        wgemm4<11,1>(av, W+W_F0, 352, ACT, AP, w,r16,g);
        int n = w*16 + r16;
        #pragma unroll
        for (int mt=0;mt<4;++mt)
            #pragma unroll
            for (int q=0;q<4;++q){
                int mrow = mt*16+g*4+q;
                float t = tanh_f(av[0][mt][q]);
                fwk[0][mt][q] = t;
                ACT[mrow*AP+352+n] = f2bf(t);
            }
    }
    __syncthreads();

    // ======== f0g GLU -> fwc0 @ [0,192) ========
    if (w < 4){
        f32x4 av[2][4]; zacc(av);
        wgemm4<6,2>(av, W+W_F0G, 192, ACT+352, AP, w,r16,g);
        #pragma unroll
        for (int i=0;i<2;++i){
            int n = (w+8*i)*16 + r16;
            #pragma unroll
            for (int mt=0;mt<4;++mt)
                #pragma unroll
                for (int q=0;q<4;++q){
                    int mrow = mt*16+g*4+q;
                    ACT[mrow*AP+n] = f2bf(fwk[i][mt][q]*sigm(av[i][mt][q]));
                }
        }
    } else {
        f32x4 av[1][4]; zacc(av);
        wgemm4<6,1>(av, W+W_F0G, 192, ACT+352, AP, w,r16,g);
        int n = w*16 + r16;
        #pragma unroll
        for (int mt=0;mt<4;++mt)
            #pragma unroll
            for (int q=0;q<4;++q){
                int mrow = mt*16+g*4+q;
                ACT[mrow*AP+n] = f2bf(fwk[0][mt][q]*sigm(av[0][mt][q]));
            }
    }
    __syncthreads();

    // ======== pitch gain (redundant per wave; wave0 writes) ========
    {
        f32x4 av[1][4]; zacc(av);
        wgemm4<6,1>(av, W+W_PG, 192, ACT, AP, 0, r16, g);
        if (w==0 && r16<4){
            float bp = b_pg[r16];
            #pragma unroll
            for (int mt=0;mt<4;++mt)
                #pragma unroll
                for (int q=0;q<4;++q)
                    PGs[mt*16+g*4+q][r16] = sigm(av[0][mt][q] + bp);
        }
    }
    __syncthreads();

    // ======== pf1 @[192,232); prev -> stable [232,272) ========
    for (int i=c8;i<40;i+=8){
        ACT[rr*AP+192+i] = f2bf(PGs[rr][0]*bf2f(FPITCHb[rr*40+i]));
        ACT[rr*AP+232+i] = ACT[rr*AP+288+i];
    }
    __syncthreads();

    // ======== GRU1 merged h-phase ========
    float hk1[2][4][4];
    if (w < 4) gru1_h<2>(W, ACT, s1, out, hk1, row0, w,r16,g);
    else       gru1_h<1>(W, ACT, s1, out, hk1, row0, w,r16,g);
    __syncthreads();

    // ======== GLU1 -> g1 @[288,448); stage s2 -> [544,672), pf2@448, prev2@488, z@528 ========
    if (w < 4) glu1<2>(W, ACT, hk1, w,r16,g); else glu1<1>(W, ACT, hk1, w,r16,g);
    {
        const float4* s24 = (const float4*)(s2 + grow*128);
        for (int i=c8;i<32;i+=8)
            *(short4v*)&ACT[rr*AP + 544 + 4*i] = pack4(s24[i]);
    }
    for (int i=c8;i<40;i+=8){
        ACT[rr*AP+448+i] = f2bf(PGs[rr][1]*bf2f(FPITCHb[rr*40+i]));
        ACT[rr*AP+488+i] = ACT[rr*AP+232+i];
    }
    for (int i=528+c8;i<544;i+=8) ACT[rr*AP+i] = 0;
    __syncthreads();

    // ======== GRU2: x=[288,544) K256, h=[544,672); HB2 -> [768,896) ========
    float hk[4][4];
    gru23_h<8,4>(W+W_IH2R, W+W_IH2Z, W+W_IH2N, 256,
                 W+W_HH2R, W+W_HH2Z, W+W_HH2N, 128,
                 ACT+288, ACT+544, AP, s2, out, OH2,
                 ACT+768, AP, hk, row0, w,r16,g);
    __syncthreads();

    // ======== GLU2 -> g2 @[544,672); stage s3 -> SH, pf3@672, prev3@712, z@752 ========
    {
        f32x4 gl[1][4]; zacc(gl);
        wgemm4<4,1>(gl, W+W_GLU2, 128, ACT+768, AP, w,r16,g);
        int n = w*16 + r16;
        #pragma unroll
        for (int mt=0;mt<4;++mt)
            #pragma unroll
            for (int q=0;q<4;++q){
                int mrow = mt*16+g*4+q;
                ACT[mrow*AP+544+n] = f2bf(hk[mt][q]*sigm(gl[0][mt][q]));
            }
    }
    {
        const float4* s34 = (const float4*)(s3 + grow*128);
        for (int i=c8;i<32;i+=8)
            *(short4v*)&SH[rr*136 + 4*i] = pack4(s34[i]);
    }
    for (int i=c8;i<40;i+=8){
        ACT[rr*AP+672+i] = f2bf(PGs[rr][2]*bf2f(FPITCHb[rr*40+i]));
        ACT[rr*AP+712+i] = ACT[rr*AP+232+i];
    }
    for (int i=752+c8;i<768;i+=8) ACT[rr*AP+i] = 0;
    __syncthreads();

    // ======== GRU3: x=[544,768) K224, h=SH (pitch 136); hk kept in regs ========
    gru23_h<7,4>(W+W_IH3R, W+W_IH3Z, W+W_IH3N, 224,
                 W+W_HH3R, W+W_HH3Z, W+W_HH3N, 128,
                 ACT+544, SH, 136, s3, out, OH3,
                 (uint16_t*)nullptr, 0, hk, row0, w,r16,g);
    __syncthreads();

    // ======== HB3 -> SH (s3 dead) ========
    {
        int n = w*16 + r16;
        #pragma unroll
        for (int mt=0;mt<4;++mt)
            #pragma unroll
            for (int q=0;q<4;++q)
                SH[(mt*16+g*4+q)*136 + n] = f2bf(hk[mt][q]);
    }
    __syncthreads();

    // ======== GLU3 (reads SH, pitch 136) -> g3 @[768,896); pf4@896 ========
    {
        f32x4 gl[1][4]; zacc(gl);
        {
            const uint16_t* ap = SH + r16*136 + g*8;
            const uint16_t* bbase = W + W_GLU3 + (size_t)(w*16 + r16)*128 + g*8;
            short8 ring[4];
            #pragma unroll
            for (int t=0;t<4;++t) ring[t] = *(const short8*)(bbase + t*32);
            #pragma unroll
            for (int s=0;s<4;++s){
                short8 af[4];
                #pragma unroll
                for (int mt=0;mt<4;++mt) af[mt] = *(const short8*)(ap + mt*16*136 + s*32);
                short8 bf = ring[s];
                #pragma unroll
                for (int mt=0;mt<4;++mt)
                    gl[0][mt] = __builtin_amdgcn_mfma_f32_16x16x32_bf16(af[mt], bf, gl[0][mt],0,0,0);
            }
        }
        int n = w*16 + r16;
        #pragma unroll
        for (int mt=0;mt<4;++mt)
            #pragma unroll
            for (int q=0;q<4;++q){
                int mrow = mt*16+g*4+q;
                ACT[mrow*AP+768+n] = f2bf(hk[mt][q]*sigm(gl[0][mt][q]));
            }
    }
    for (int i=c8;i<40;i+=8)
        ACT[rr*AP+896+i] = f2bf(PGs[rr][3]*bf2f(FPITCHb[rr*40+i]));
    __syncthreads();

    // ======== skip: tanh(ACT[0,960) @ W_SKIP^T) -> SK @ SH ========
    float skk[4][4];
    {
        f32x4 av[1][4]; zacc(av);
        wgemm4<30,1>(av, W+W_SKIP, 960, ACT, AP, w,r16,g);
        int n = w*16 + r16;
        #pragma unroll
        for (int mt=0;mt<4;++mt)
            #pragma unroll
            for (int q=0;q<4;++q){
                int mrow = mt*16+g*4+q;
                float t = tanh_f(av[0][mt][q]);
                skk[mt][q] = t;
                SH[mrow*136+n] = f2bf(t);
            }
    }
    __syncthreads();
    // ======== skip GLU (reads SH, pitch 136) -> SK2 @ ACT[0,128) ========
    {
        f32x4 av[1][4]; zacc(av);
        {
            const uint16_t* ap = SH + r16*136 + g*8;
            const uint16_t* bbase = W + W_SKIPG + (size_t)(w*16 + r16)*128 + g*8;
            short8 ring[4];
            #pragma unroll
            for (int t=0;t<4;++t) ring[t] = *(const short8*)(bbase + t*32);
            #pragma unroll
            for (int s=0;s<4;++s){
                short8 af[4];
                #pragma unroll
                for (int mt=0;mt<4;++mt) af[mt] = *(const short8*)(ap + mt*16*136 + s*32);
                short8 bf = ring[s];
                #pragma unroll
                for (int mt=0;mt<4;++mt)
                    av[0][mt] = __builtin_amdgcn_mfma_f32_16x16x32_bf16(af[mt], bf, av[0][mt],0,0,0);
            }
        }
        int n = w*16 + r16;
        #pragma unroll
        for (int mt=0;mt<4;++mt)
            #pragma unroll
            for (int q=0;q<4;++q){
                int mrow = mt*16+g*4+q;
                ACT[mrow*AP+n] = f2bf(skk[mt][q]*sigm(av[0][mt][q]));
            }
    }
    __syncthreads();
    // ======== sig: waves 0-3 (Npad=64), valid n<40 ========
    if (w < 4){
        f32x4 av[1][4]; zacc(av);
        wgemm4<4,1>(av, W+W_SIG, 128, ACT, AP, w,r16,g);
        int n = w*16 + r16;
        if (n < 40){
            #pragma unroll
            for (int mt=0;mt<4;++mt)
                #pragma unroll
                for (int q=0;q<4;++q){
                    int mrow = mt*16+g*4+q;
                    float sv = tanh_f(av[0][mt][q]) * GAIN[mrow];
                    out[OSIG + (long)(row0+mrow)*40 + n] = sv;
                    out[OEXC + (long)(row0+mrow)*256 + 216 + n] = sv;
                }
        }
    }
}

extern "C" void kernel_launch(void* const* d_in, const int* in_sizes, int n_in,
                              void* d_out, int out_size, void* d_ws, size_t ws_size,
                              hipStream_t stream) {
    const float* cond      = (const float*)d_in[0];
    const float* prev_pred = (const float*)d_in[1];
    const float* exc_mem   = (const float*)d_in[2];
    const float* period    = (const float*)d_in[3];
    const float* s1        = (const float*)d_in[4];
    const float* s2        = (const float*)d_in[5];
    const float* s3        = (const float*)d_in[6];
    const float* s4        = (const float*)d_in[7];
    const float* w_gain    = (const float*)d_in[8];
    const float* b_gain    = (const float*)d_in[9];
    const float* w_fwc0    = (const float*)d_in[10];
    const float* w_fwc0_glu= (const float*)d_in[11];
    const float* wih1      = (const float*)d_in[12];
    const float* whh1      = (const float*)d_in[13];
    const float* wglu1     = (const float*)d_in[14];
    const float* wih2      = (const float*)d_in[15];
    const float* whh2      = (const float*)d_in[16];
    const float* wglu2     = (const float*)d_in[17];
    const float* wih3      = (const float*)d_in[18];
    const float* whh3      = (const float*)d_in[19];
    const float* wglu3     = (const float*)d_in[20];
    const float* w_skip    = (const float*)d_in[21];
    const float* w_skip_glu= (const float*)d_in[22];
    const float* w_sig     = (const float*)d_in[23];
    const float* w_pg      = (const float*)d_in[24];
    const float* b_pg      = (const float*)d_in[25];
    float* out = (float*)d_out;
    uint16_t* wsbf = (uint16_t*)d_ws;

    PrepArgs pa;
    pa.s[0]=w_fwc0; pa.s[1]=w_fwc0_glu; pa.s[2]=wih1; pa.s[3]=whh1; pa.s[4]=wglu1;
    pa.s[5]=wih2; pa.s[6]=whh2; pa.s[7]=wglu2; pa.s[8]=wih3; pa.s[9]=whh3;
    pa.s[10]=wglu3; pa.s[11]=w_skip; pa.s[12]=w_skip_glu; pa.s[13]=w_pg; pa.s[14]=w_sig;

    hipLaunchKernelGGL(prep_kernel, dim3(3856), dim3(64), 0, stream, pa, wsbf);
    hipLaunchKernelGGL(fargan_mfma, dim3(512), dim3(512), 0, stream,
        cond, prev_pred, exc_mem, period, s1, s2, s3, s4,
        w_gain, b_gain, b_pg, wsbf, out);
}

// Round 16
// 211.292 us; speedup vs baseline: 1.2876x; 1.0884x over previous
//
#include <hip/hip_runtime.h>
#include <hip/hip_bf16.h>
#include <cstdint>
#include <cmath>

#define BTOT 32768L
#define OSIG 0L
#define OEXC (BTOT*40L)
#define OPREV (OEXC + BTOT*256L)
#define OH1 (OPREV + BTOT*256L)
#define OH2 (OH1 + BTOT*160L)
#define OH3 (OH2 + BTOT*128L)
#define ONS4 (OH3 + BTOT*128L)

typedef __attribute__((ext_vector_type(8))) short short8;
typedef __attribute__((ext_vector_type(4))) short short4v;
typedef __attribute__((ext_vector_type(4))) float f32x4;

#define AP 968   // ACT pitch (bf16 elems)

// ACT column map: identical to R10 lifetime audit; 64 rows.
#define W_F0     0L        // [192][352]
#define W_F0G    67584L    // [192][192]
#define W_PG     104448L   // [16][192]
#define W_IH1R   107520L   // [192][288]
#define W_IH1Z   162816L
#define W_IH1N   218112L
#define W_HH1R   273408L   // [192][192]
#define W_HH1Z   310272L
#define W_HH1N   347136L
#define W_GLU1   384000L   // [192][192]
#define W_IH2R   420864L   // [128][256]
#define W_IH2Z   453632L
#define W_IH2N   486400L
#define W_HH2R   519168L   // [128][128]
#define W_HH2Z   535552L
#define W_HH2N   551936L
#define W_GLU2   568320L   // [128][128]
#define W_IH3R   584704L   // [128][224]
#define W_IH3Z   613376L
#define W_IH3N   642048L
#define W_HH3R   670720L   // [128][128]
#define W_HH3Z   687104L
#define W_HH3N   703488L
#define W_GLU3   719872L   // [128][128]
#define W_SKIP   736256L   // [128][960] column-permuted to ACT map
#define W_SKIPG  859136L   // [128][128]
#define W_SIG    875520L   // [64][128]

__device__ __forceinline__ float sigm(float x){ return 1.0f/(1.0f+__expf(-x)); }
__device__ __forceinline__ float tanh_f(float x){
    float e = __expf(2.0f*x);
    return 1.0f - 2.0f/(e+1.0f);
}
__device__ __forceinline__ uint16_t f2bf(float x){
    __hip_bfloat16 h = __float2bfloat16(x);
    return *(uint16_t*)&h;
}
__device__ __forceinline__ float bf2f(uint16_t h){
    union { float f; uint32_t u; } v; v.u = ((uint32_t)h)<<16;
    return v.f;
}
__device__ __forceinline__ short4v pack4(float4 v){
    short4v r;
    r.x=(short)f2bf(v.x); r.y=(short)f2bf(v.y); r.z=(short)f2bf(v.z); r.w=(short)f2bf(v.w);
    return r;
}

// ---------------- prep: fp32 weights -> padded bf16 blocks in ws ----------------
struct PrepArgs { const float* s[15]; };

__global__ __launch_bounds__(64) void prep_kernel(PrepArgs pa, uint16_t* dst){
    static const long J[27][8] = {
        {0,  0,192,328,352,192, W_F0,   0},
        {1,  0,192,192,192,192, W_F0G,  0},
        {13, 0,  4,192,192, 16, W_PG,   0},
        {2,  0,160,272,288,192, W_IH1R, 0},
        {2,160,160,272,288,192, W_IH1Z, 0},
        {2,320,160,272,288,192, W_IH1N, 0},
        {3,  0,160,160,192,192, W_HH1R, 0},
        {3,160,160,160,192,192, W_HH1Z, 0},
        {3,320,160,160,192,192, W_HH1N, 0},
        {4,  0,160,160,192,192, W_GLU1, 0},
        {5,  0,128,240,256,128, W_IH2R, 0},
        {5,128,128,240,256,128, W_IH2Z, 0},
        {5,256,128,240,256,128, W_IH2N, 0},
        {6,  0,128,128,128,128, W_HH2R, 0},
        {6,128,128,128,128,128, W_HH2Z, 0},
        {6,256,128,128,128,128, W_HH2N, 0},
        {7,  0,128,128,128,128, W_GLU2, 0},
        {8,  0,128,208,224,128, W_IH3R, 0},
        {8,128,128,208,224,128, W_IH3Z, 0},
        {8,256,128,208,224,128, W_IH3N, 0},
        {9,  0,128,128,128,128, W_HH3R, 0},
        {9,128,128,128,128,128, W_HH3Z, 0},
        {9,256,128,128,128,128, W_HH3N, 0},
        {10, 0,128,128,128,128, W_GLU3, 0},
        {11, 0,128,688,960,128, W_SKIP, 1},
        {12, 0,128,128,128,128, W_SKIPG,0},
        {14, 0, 40,128,128, 64, W_SIG,  0},
    };
    long row = blockIdx.x;
    int j = 0;
    while (row >= J[j][5]) { row -= J[j][5]; ++j; }
    const float* src = pa.s[J[j][0]];
    const long ro = J[j][1], N = J[j][2], K = J[j][3], KP = J[j][4];
    const int type = (int)J[j][7];
    uint16_t* d = dst + J[j][6] + row*KP;
    for (long k = threadIdx.x; k < KP; k += 64){
        float v = 0.0f;
        if (row < N){
            if (type == 0){
                if (k < K) v = src[(ro+row)*K + k];
            } else {
                long s = -1;
                if (k < 192) s = 416 + k;                        // fwc0
                else if (k >= 232 && k < 272) s = 648 + (k-232); // prev
                else if (k >= 288 && k < 448) s = (k-288);       // g1
                else if (k >= 544 && k < 672) s = 160 + (k-544); // g2
                else if (k >= 768 && k < 896) s = 288 + (k-768); // g3
                else if (k >= 896 && k < 936) s = 608 + (k-896); // pf4
                if (s >= 0) v = src[row*688 + s];
            }
        }
        d[k] = f2bf(v);
    }
}

// ---------------- quad-m-tile wave GEMM (single B), ring prefetch ----------------
template<int KS, int CNT>
__device__ __forceinline__ void wgemm4(f32x4 (&acc)[CNT][4],
    const uint16_t* __restrict__ Bw, int KP,
    const uint16_t* A, int P, int w, int r16, int g)
{
    constexpr int T = KS*CNT;
    constexpr int PF = (T < 12) ? T : 12;
    const uint16_t* ap = A + r16*P + g*8;
    const uint16_t* bbase = Bw + (size_t)(w*16 + r16)*KP + g*8;
    short8 ring[PF];
    #pragma unroll
    for (int t=0;t<PF;++t)
        ring[t] = *(const short8*)(bbase + (size_t)(t%CNT)*128*KP + (size_t)(t/CNT)*32);
    short8 af[4];
    #pragma unroll
    for (int t=0;t<T;++t){
        const int s = t/CNT, i = t%CNT;
        if (i==0){
            #pragma unroll
            for (int mt=0;mt<4;++mt) af[mt] = *(const short8*)(ap + mt*16*P + s*32);
        }
        short8 bf = ring[t%PF];
        if (t+PF < T)
            ring[t%PF] = *(const short8*)(bbase + (size_t)((t+PF)%CNT)*128*KP + (size_t)((t+PF)/CNT)*32);
        #pragma unroll
        for (int mt=0;mt<4;++mt)
            acc[i][mt] = __builtin_amdgcn_mfma_f32_16x16x32_bf16(af[mt], bf, acc[i][mt],0,0,0);
    }
}

// ---------------- fused 3-gate GEMM: one A-fragment feeds 12 MFMAs ----------------
template<int KS, int CNT>
__device__ __forceinline__ void wgemm3(
    f32x4 (&a0)[CNT][4], f32x4 (&a1)[CNT][4], f32x4 (&a2)[CNT][4],
    const uint16_t* __restrict__ B0, const uint16_t* __restrict__ B1,
    const uint16_t* __restrict__ B2, int KP,
    const uint16_t* A, int P, int w, int r16, int g)
{
    constexpr int T = KS*CNT;
    constexpr int PF = (T < 4) ? T : 4;
    const uint16_t* ap = A + r16*P + g*8;
    const size_t boff = (size_t)(w*16 + r16)*KP + g*8;
    const uint16_t* b0 = B0 + boff;
    const uint16_t* b1 = B1 + boff;
    const uint16_t* b2 = B2 + boff;
    short8 r0[PF], r1[PF], r2[PF];
    #pragma unroll
    for (int t=0;t<PF;++t){
        size_t o = (size_t)(t%CNT)*128*KP + (size_t)(t/CNT)*32;
        r0[t] = *(const short8*)(b0 + o);
        r1[t] = *(const short8*)(b1 + o);
        r2[t] = *(const short8*)(b2 + o);
    }
    short8 af[4];
    #pragma unroll
    for (int t=0;t<T;++t){
        const int i = t%CNT;
        if (i==0){
            const int s = t/CNT;
            #pragma unroll
            for (int mt=0;mt<4;++mt) af[mt] = *(const short8*)(ap + mt*16*P + s*32);
        }
        short8 f0 = r0[t%PF], f1 = r1[t%PF], f2 = r2[t%PF];
        if (t+PF < T){
            size_t o = (size_t)((t+PF)%CNT)*128*KP + (size_t)((t+PF)/CNT)*32;
            r0[t%PF] = *(const short8*)(b0 + o);
            r1[t%PF] = *(const short8*)(b1 + o);
            r2[t%PF] = *(const short8*)(b2 + o);
        }
        #pragma unroll
        for (int mt=0;mt<4;++mt){
            a0[i][mt] = __builtin_amdgcn_mfma_f32_16x16x32_bf16(af[mt], f0, a0[i][mt],0,0,0);
            a1[i][mt] = __builtin_amdgcn_mfma_f32_16x16x32_bf16(af[mt], f1, a1[i][mt],0,0,0);
            a2[i][mt] = __builtin_amdgcn_mfma_f32_16x16x32_bf16(af[mt], f2, a2[i][mt],0,0,0);
        }
    }
}
template<int CNT> __device__ __forceinline__ void zacc(f32x4 (&a)[CNT][4]){
    f32x4 z4 = {0.f,0.f,0.f,0.f};
    #pragma unroll
    for (int i=0;i<CNT;++i){
        #pragma unroll
        for (int mt=0;mt<4;++mt) a[i][mt]=z4;
    }
}

// ---------------- GRU1 merged h-phase (H=160, x=[0,288) K288, h=[544,736) K192) ----------------
template<int CNT>
__device__ __forceinline__ void gru1_h(const uint16_t* __restrict__ W, uint16_t* ACTp,
    const float* __restrict__ s1g, float* __restrict__ out,
    float (&hk)[2][4][4], int row0, int w, int r16, int g)
{
    f32x4 gx[CNT][4], gh[CNT][4], ra[CNT][4], za[CNT][4];
    zacc(gx); zacc(gh); zacc(ra); zacc(za);
    wgemm3<9,CNT>(gx, ra, za, W+W_IH1N, W+W_IH1R, W+W_IH1Z, 288, ACTp,     AP, w,r16,g);
    wgemm3<6,CNT>(gh, ra, za, W+W_HH1N, W+W_HH1R, W+W_HH1Z, 192, ACTp+544, AP, w,r16,g);
    #pragma unroll
    for (int i=0;i<CNT;++i){
        int n = (w+8*i)*16 + r16;
        #pragma unroll
        for (int mt=0;mt<4;++mt){
            #pragma unroll
            for (int q=0;q<4;++q){
                int mrow = mt*16+g*4+q;
                float h = 0.f;
                if (n < 160){
                    float hpv = s1g[(long)(row0+mrow)*160 + n];
                    float r = sigm(ra[i][mt][q]);
                    float z = sigm(za[i][mt][q]);
                    float nn = tanh_f(gx[i][mt][q] + r*gh[i][mt][q]);
                    h = (1.f-z)*nn + z*hpv;
                    out[OH1 + (long)(row0+mrow)*160 + n] = h;
                }
                hk[i][mt][q] = h;
                ACTp[mrow*AP+768+n] = f2bf(h);   // HB1 (h; zeros n>=160)
            }
        }
    }
}
template<int CNT>
__device__ __forceinline__ void glu1(const uint16_t* __restrict__ W, uint16_t* ACTp,
                                     float (&hk)[2][4][4], int w, int r16, int g){
    f32x4 gl[CNT][4];
    zacc(gl);
    wgemm4<6,CNT>(gl, W+W_GLU1, 192, ACTp+768, AP, w,r16,g);
    #pragma unroll
    for (int i=0;i<CNT;++i){
        int n = (w+8*i)*16 + r16;
        if (n < 160){
            #pragma unroll
            for (int mt=0;mt<4;++mt)
                #pragma unroll
                for (int q=0;q<4;++q){
                    int mrow = mt*16+g*4+q;
                    ACTp[mrow*AP + 288 + n] = f2bf(hk[i][mt][q]*sigm(gl[i][mt][q]));  // g1
                }
        }
    }
}

// ---------------- GRU2/3 merged h-phase (H=128) ----------------
template<int KSX, int KSH>
__device__ __forceinline__ void gru23_h(
    const uint16_t* __restrict__ Wxr, const uint16_t* __restrict__ Wxz, const uint16_t* __restrict__ Wxn, int KPX,
    const uint16_t* __restrict__ Whr, const uint16_t* __restrict__ Whz, const uint16_t* __restrict__ Whn, int KPH,
    const uint16_t* XA, const uint16_t* HA, int HAP,
    const float* __restrict__ sg, float* __restrict__ outp, long obase,
    uint16_t* HBdst, int HBpitch,
    float (&hk)[4][4], int row0, int w, int r16, int g)
{
    const int n = w*16 + r16;
    f32x4 gx[1][4], gh[1][4], ra[1][4], za[1][4];
    zacc(gx); zacc(gh); zacc(ra); zacc(za);
    wgemm3<KSX,1>(gx, ra, za, Wxn, Wxr, Wxz, KPX, XA, AP, w,r16,g);
    wgemm3<KSH,1>(gh, ra, za, Whn, Whr, Whz, KPH, HA, HAP, w,r16,g);
    #pragma unroll
    for (int mt=0;mt<4;++mt){
        #pragma unroll
        for (int q=0;q<4;++q){
            int mrow = mt*16+g*4+q;
            float hpv = sg[(long)(row0+mrow)*128 + n];
            float r = sigm(ra[0][mt][q]), z = sigm(za[0][mt][q]);
            float nn = tanh_f(gx[0][mt][q] + r*gh[0][mt][q]);
            float h = (1.f-z)*nn + z*hpv;
            outp[obase + (long)(row0+mrow)*128 + n] = h;
            hk[mt][q] = h;
            if (HBdst) HBdst[mrow*HBpitch + n] = f2bf(h);
        }
    }
}

// ---------------- main kernel: 64 rows / block, 512 threads, 1 block/CU ----------------
extern "C" __global__ __launch_bounds__(512, 2)
void fargan_mfma(const float* __restrict__ cond, const float* __restrict__ prev_pred,
                 const float* __restrict__ exc_mem, const float* __restrict__ period,
                 const float* __restrict__ s1, const float* __restrict__ s2,
                 const float* __restrict__ s3, const float* __restrict__ s4,
                 const float* __restrict__ w_gain, const float* __restrict__ b_gain,
                 const float* __restrict__ b_pg,
                 const uint16_t* __restrict__ W, float* __restrict__ out)
{
    __shared__ __align__(16) uint16_t ACT[64*AP];
    __shared__ __align__(16) uint16_t SH[64*136];
    __shared__ uint16_t FPITCHb[64*40];
    __shared__ float GAIN[64];
    __shared__ float PGs[64][4];

    const int tid = threadIdx.x;
    const int row0 = blockIdx.x * 64;
    const int w = tid >> 6, l = tid & 63, r16 = l & 15, g = l >> 4;
    const int rr = tid >> 3, c8 = tid & 7;
    const long grow = row0 + rr;

    // ======== stage A (float4-vectorized) ========
    const float* exc_row = exc_mem + grow*256;

    float a0 = 0.f;
    {
        const float4* c4 = (const float4*)(cond + grow*80);
        const float4* g4 = (const float4*)w_gain;
        float4* on4 = (float4*)(out + ONS4 + grow*164);
        for (int i=c8;i<20;i+=8){
            float4 cv = c4[i], gv = g4[i];
            a0 += cv.x*gv.x + cv.y*gv.y + cv.z*gv.z + cv.w*gv.w;
            *(short4v*)&ACT[rr*AP + 164 + 4*i] = pack4(cv);
            on4[i] = cv;
        }
    }
    a0 += __shfl_xor(a0,4,8); a0 += __shfl_xor(a0,2,8); a0 += __shfl_xor(a0,1,8);
    float gn = 0.2f + 0.8f*sigm(a0 + b_gain[0]);
    if (!(gn==gn)) gn = 1.0f;
    gn = fminf(fmaxf(gn, 0.001f), 20.0f);
    float inv = 1.0f/(1e-5f+gn);
    if (c8==0) GAIN[rr] = gn;

    float p = period[grow];
    p = (fabsf(p) <= 3.0e38f) ? p : 128.0f;
    p = fminf(fmaxf(p, 32.0f), 255.0f);

    for (int e=c8;e<44;e+=8){
        float idxf = 254.0f - p + (float)e;
        float idx0 = floorf(idxf);
        float al = fminf(fmaxf(idxf-idx0, 0.f), 1.f);
        int i0 = (int)fminf(fmaxf(idx0, 0.f), 255.f);
        int i1 = (int)fminf(fmaxf(idx0+1.f, 0.f), 255.f);
        float pr = (1.f-al)*exc_row[i0] + al*exc_row[i1];
        float pn = pr*inv;
        ACT[rr*AP + 244 + e] = f2bf(pn);             // XCAT pred_n
        out[ONS4 + grow*164 + 80 + e] = pn;
        if (e>=2 && e<42){
            out[OPREV + grow*256 + 216 + (e-2)] = pr;
            FPITCHb[rr*40 + (e-2)] = f2bf(pn);
        }
    }
    {
        const float4* pv4 = (const float4*)(exc_row + 216);
        float4* onp = (float4*)(out + ONS4 + grow*164 + 124);
        for (int i=c8;i<10;i+=8){
            float4 v = pv4[i];
            v.x*=inv; v.y*=inv; v.z*=inv; v.w*=inv;
            *(short4v*)&ACT[rr*AP + 288 + 4*i] = pack4(v);   // XCAT prev (stable until GLU1)
            onp[i] = v;
        }
    }
    {
        const float4* s44 = (const float4*)(s4 + grow*164);
        for (int i=c8;i<41;i+=8)
            *(short4v*)&ACT[rr*AP + 4*i] = pack4(s44[i]);    // XCAT s4
        const float4* s14 = (const float4*)(s1 + grow*160);
        for (int i=c8;i<40;i+=8)
            *(short4v*)&ACT[rr*AP + 544 + 4*i] = pack4(s14[i]);  // s1-state
    }
    for (int i=328+c8;i<352;i+=8) ACT[rr*AP + i] = 0;            // XCAT pad
    for (int i=704+c8;i<736;i+=8) ACT[rr*AP + i] = 0;            // s1 pad
    {
        const float4* pp4 = (const float4*)(prev_pred + grow*256 + 40);
        const float4* ex4 = (const float4*)(exc_row + 40);
        float4* op4 = (float4*)(out + OPREV + grow*256);
        float4* oe4 = (float4*)(out + OEXC + grow*256);
        for (int i=c8;i<54;i+=8){ op4[i] = pp4[i]; oe4[i] = ex4[i]; }
    }
    __syncthreads();

    float fwk[2][4][4];

    // ======== fwc0: tanh(XCAT[0,352) @ W_F0^T) -> FWRAW @ [352,544) ========
    if (w < 4){
        f32x4 av[2][4]; zacc(av);
        wgemm4<11,2>(av, W+W_F0, 352, ACT, AP, w,r16,g);
        #pragma unroll
        for (int i=0;i<2;++i){
            int n = (w+8*i)*16 + r16;
            #pragma unroll
            for (int mt=0;mt<4;++mt)
                #pragma unroll
                for (int q=0;q<4;++q){
                    int mrow = mt*16+g*4+q;
                    float t = tanh_f(av[i][mt][q]);
                    fwk[i][mt][q] = t;
                    ACT[mrow*AP+352+n] = f2bf(t);
                }
        }
    } else {
        f32x4 av[1][4]; zacc(av);
        wgemm4<11,1>(av, W+W_F0, 352, ACT, AP, w,r16,g);
        int n = w*16 + r16;
        #pragma unroll
        for (int mt=0;mt<4;++mt)
            #pragma unroll
            for (int q=0;q<4;++q){
                int mrow = mt*16+g*4+q;
                float t = tanh_f(av[0][mt][q]);
                fwk[0][mt][q] = t;
                ACT[mrow*AP+352+n] = f2bf(t);
            }
    }
    __syncthreads();

    // ======== f0g GLU -> fwc0 @ [0,192) ========
    if (w < 4){
        f32x4 av[2][4]; zacc(av);
        wgemm4<6,2>(av, W+W_F0G, 192, ACT+352, AP, w,r16,g);
        #pragma unroll
        for (int i=0;i<2;++i){
            int n = (w+8*i)*16 + r16;
            #pragma unroll
            for (int mt=0;mt<4;++mt)
                #pragma unroll
                for (int q=0;q<4;++q){
                    int mrow = mt*16+g*4+q;
                    ACT[mrow*AP+n] = f2bf(fwk[i][mt][q]*sigm(av[i][mt][q]));
                }
        }
    } else {
        f32x4 av[1][4]; zacc(av);
        wgemm4<6,1>(av, W+W_F0G, 192, ACT+352, AP, w,r16,g);
        int n = w*16 + r16;
        #pragma unroll
        for (int mt=0;mt<4;++mt)
            #pragma unroll
            for (int q=0;q<4;++q){
                int mrow = mt*16+g*4+q;
                ACT[mrow*AP+n] = f2bf(fwk[0][mt][q]*sigm(av[0][mt][q]));
            }
    }
    __syncthreads();

    // ======== pitch gain (redundant per wave; wave0 writes) ========
    {
        f32x4 av[1][4]; zacc(av);
        wgemm4<6,1>(av, W+W_PG, 192, ACT, AP, 0, r16, g);
        if (w==0 && r16<4){
            float bp = b_pg[r16];
            #pragma unroll
            for (int mt=0;mt<4;++mt)
                #pragma unroll
                for (int q=0;q<4;++q)
                    PGs[mt*16+g*4+q][r16] = sigm(av[0][mt][q] + bp);
        }
    }
    __syncthreads();

    // ======== pf1 @[192,232); prev -> stable [232,272) ========
    for (int i=c8;i<40;i+=8){
        ACT[rr*AP+192+i] = f2bf(PGs[rr][0]*bf2f(FPITCHb[rr*40+i]));
        ACT[rr*AP+232+i] = ACT[rr*AP+288+i];
    }
    __syncthreads();

    // ======== GRU1 merged h-phase (fused 3-gate GEMMs) ========
    float hk1[2][4][4];
    if (w < 4) gru1_h<2>(W, ACT, s1, out, hk1, row0, w,r16,g);
    else       gru1_h<1>(W, ACT, s1, out, hk1, row0, w,r16,g);
    __syncthreads();

    // ======== GLU1 -> g1 @[288,448); stage s2 -> [544,672), pf2@448, prev2@488, z@528 ========
    if (w < 4) glu1<2>(W, ACT, hk1, w,r16,g); else glu1<1>(W, ACT, hk1, w,r16,g);
    {
        const float4* s24 = (const float4*)(s2 + grow*128);
        for (int i=c8;i<32;i+=8)
            *(short4v*)&ACT[rr*AP + 544 + 4*i] = pack4(s24[i]);
    }
    for (int i=c8;i<40;i+=8){
        ACT[rr*AP+448+i] = f2bf(PGs[rr][1]*bf2f(FPITCHb[rr*40+i]));
        ACT[rr*AP+488+i] = ACT[rr*AP+232+i];
    }
    for (int i=528+c8;i<544;i+=8) ACT[rr*AP+i] = 0;
    __syncthreads();

    // ======== GRU2: x=[288,544) K256, h=[544,672); HB2 -> [768,896) ========
    float hk[4][4];
    gru23_h<8,4>(W+W_IH2R, W+W_IH2Z, W+W_IH2N, 256,
                 W+W_HH2R, W+W_HH2Z, W+W_HH2N, 128,
                 ACT+288, ACT+544, AP, s2, out, OH2,
                 ACT+768, AP, hk, row0, w,r16,g);
    __syncthreads();

    // ======== GLU2 -> g2 @[544,672); stage s3 -> SH, pf3@672, prev3@712, z@752 ========
    {
        f32x4 gl[1][4]; zacc(gl);
        wgemm4<4,1>(gl, W+W_GLU2, 128, ACT+768, AP, w,r16,g);
        int n = w*16 + r16;
        #pragma unroll
        for (int mt=0;mt<4;++mt)
            #pragma unroll
            for (int q=0;q<4;++q){
                int mrow = mt*16+g*4+q;
                ACT[mrow*AP+544+n] = f2bf(hk[mt][q]*sigm(gl[0][mt][q]));
            }
    }
    {
        const float4* s34 = (const float4*)(s3 + grow*128);
        for (int i=c8;i<32;i+=8)
            *(short4v*)&SH[rr*136 + 4*i] = pack4(s34[i]);
    }
    for (int i=c8;i<40;i+=8){
        ACT[rr*AP+672+i] = f2bf(PGs[rr][2]*bf2f(FPITCHb[rr*40+i]));
        ACT[rr*AP+712+i] = ACT[rr*AP+232+i];
    }
    for (int i=752+c8;i<768;i+=8) ACT[rr*AP+i] = 0;
    __syncthreads();

    // ======== GRU3: x=[544,768) K224, h=SH (pitch 136); hk kept in regs ========
    gru23_h<7,4>(W+W_IH3R, W+W_IH3Z, W+W_IH3N, 224,
                 W+W_HH3R, W+W_HH3Z, W+W_HH3N, 128,
                 ACT+544, SH, 136, s3, out, OH3,
                 (uint16_t*)nullptr, 0, hk, row0, w,r16,g);
    __syncthreads();

    // ======== HB3 -> SH (s3 dead) ========
    {
        int n = w*16 + r16;
        #pragma unroll
        for (int mt=0;mt<4;++mt)
            #pragma unroll
            for (int q=0;q<4;++q)
                SH[(mt*16+g*4+q)*136 + n] = f2bf(hk[mt][q]);
    }
    __syncthreads();

    // ======== GLU3 (reads SH, pitch 136) -> g3 @[768,896); pf4@896 ========
    {
        f32x4 gl[1][4]; zacc(gl);
        {
            const uint16_t* ap = SH + r16*136 + g*8;
            const uint16_t* bbase = W + W_GLU3 + (size_t)(w*16 + r16)*128 + g*8;
            short8 ring[4];
            #pragma unroll
            for (int t=0;t<4;++t) ring[t] = *(const short8*)(bbase + t*32);
            #pragma unroll
            for (int s=0;s<4;++s){
                short8 af[4];
                #pragma unroll
                for (int mt=0;mt<4;++mt) af[mt] = *(const short8*)(ap + mt*16*136 + s*32);
                short8 bf = ring[s];
                #pragma unroll
                for (int mt=0;mt<4;++mt)
                    gl[0][mt] = __builtin_amdgcn_mfma_f32_16x16x32_bf16(af[mt], bf, gl[0][mt],0,0,0);
            }
        }
        int n = w*16 + r16;
        #pragma unroll
        for (int mt=0;mt<4;++mt)
            #pragma unroll
            for (int q=0;q<4;++q){
                int mrow = mt*16+g*4+q;
                ACT[mrow*AP+768+n] = f2bf(hk[mt][q]*sigm(gl[0][mt][q]));
            }
    }
    for (int i=c8;i<40;i+=8)
        ACT[rr*AP+896+i] = f2bf(PGs[rr][3]*bf2f(FPITCHb[rr*40+i]));
    __syncthreads();

    // ======== skip: tanh(ACT[0,960) @ W_SKIP^T) -> SK @ SH ========
    float skk[4][4];
    {
        f32x4 av[1][4]; zacc(av);
        wgemm4<30,1>(av, W+W_SKIP, 960, ACT, AP, w,r16,g);
        int n = w*16 + r16;
        #pragma unroll
        for (int mt=0;mt<4;++mt)
            #pragma unroll
            for (int q=0;q<4;++q){
                int mrow = mt*16+g*4+q;
                float t = tanh_f(av[0][mt][q]);
                skk[mt][q] = t;
                SH[mrow*136+n] = f2bf(t);
            }
    }
    __syncthreads();
    // ======== skip GLU (reads SH, pitch 136) -> SK2 @ ACT[0,128) ========
    {
        f32x4 av[1][4]; zacc(av);
        {
            const uint16_t* ap = SH + r16*136 + g*8;
            const uint16_t* bbase = W + W_SKIPG + (size_t)(w*16 + r16)*128 + g*8;
            short8 ring[4];
            #pragma unroll
            for (int t=0;t<4;++t) ring[t] = *(const short8*)(bbase + t*32);
            #pragma unroll
            for (int s=0;s<4;++s){
                short8 af[4];
                #pragma unroll
                for (int mt=0;mt<4;++mt) af[mt] = *(const short8*)(ap + mt*16*136 + s*32);
                short8 bf = ring[s];
                #pragma unroll
                for (int mt=0;mt<4;++mt)
                    av[0][mt] = __builtin_amdgcn_mfma_f32_16x16x32_bf16(af[mt], bf, av[0][mt],0,0,0);
            }
        }
        int n = w*16 + r16;
        #pragma unroll
        for (int mt=0;mt<4;++mt)
            #pragma unroll
            for (int q=0;q<4;++q){
                int mrow = mt*16+g*4+q;
                ACT[mrow*AP+n] = f2bf(skk[mt][q]*sigm(av[0][mt][q]));
            }
    }
    __syncthreads();
    // ======== sig: waves 0-3 (Npad=64), valid n<40 ========
    if (w < 4){
        f32x4 av[1][4]; zacc(av);
        wgemm4<4,1>(av, W+W_SIG, 128, ACT, AP, w,r16,g);
        int n = w*16 + r16;
        if (n < 40){
            #pragma unroll
            for (int mt=0;mt<4;++mt)
                #pragma unroll
                for (int q=0;q<4;++q){
                    int mrow = mt*16+g*4+q;
                    float sv = tanh_f(av[0][mt][q]) * GAIN[mrow];
                    out[OSIG + (long)(row0+mrow)*40 + n] = sv;
                    out[OEXC + (long)(row0+mrow)*256 + 216 + n] = sv;
                }
        }
    }
}

extern "C" void kernel_launch(void* const* d_in, const int* in_sizes, int n_in,
                              void* d_out, int out_size, void* d_ws, size_t ws_size,
                              hipStream_t stream) {
    const float* cond      = (const float*)d_in[0];
    const float* prev_pred = (const float*)d_in[1];
    const float* exc_mem   = (const float*)d_in[2];
    const float* period    = (const float*)d_in[3];
    const float* s1        = (const float*)d_in[4];
    const float* s2        = (const float*)d_in[5];
    const float* s3        = (const float*)d_in[6];
    const float* s4        = (const float*)d_in[7];
    const float* w_gain    = (const float*)d_in[8];
    const float* b_gain    = (const float*)d_in[9];
    const float* w_fwc0    = (const float*)d_in[10];
    const float* w_fwc0_glu= (const float*)d_in[11];
    const float* wih1      = (const float*)d_in[12];
    const float* whh1      = (const float*)d_in[13];
    const float* wglu1     = (const float*)d_in[14];
    const float* wih2      = (const float*)d_in[15];
    const float* whh2      = (const float*)d_in[16];
    const float* wglu2     = (const float*)d_in[17];
    const float* wih3      = (const float*)d_in[18];
    const float* whh3      = (const float*)d_in[19];
    const float* wglu3     = (const float*)d_in[20];
    const float* w_skip    = (const float*)d_in[21];
    const float* w_skip_glu= (const float*)d_in[22];
    const float* w_sig     = (const float*)d_in[23];
    const float* w_pg      = (const float*)d_in[24];
    const float* b_pg      = (const float*)d_in[25];
    float* out = (float*)d_out;
    uint16_t* wsbf = (uint16_t*)d_ws;

    PrepArgs pa;
    pa.s[0]=w_fwc0; pa.s[1]=w_fwc0_glu; pa.s[2]=wih1; pa.s[3]=whh1; pa.s[4]=wglu1;
    pa.s[5]=wih2; pa.s[6]=whh2; pa.s[7]=wglu2; pa.s[8]=wih3; pa.s[9]=whh3;
    pa.s[10]=wglu3; pa.s[11]=w_skip; pa.s[12]=w_skip_glu; pa.s[13]=w_pg; pa.s[14]=w_sig;

    hipLaunchKernelGGL(prep_kernel, dim3(3856), dim3(64), 0, stream, pa, wsbf);
    hipLaunchKernelGGL(fargan_mfma, dim3(512), dim3(512), 0, stream,
        cond, prev_pred, exc_mem, period, s1, s2, s3, s4,
        w_gain, b_gain, b_pg, wsbf, out);
}